// Round 8
// baseline (146.420 us; speedup 1.0000x reference)
//
#include <hip/hip_runtime.h>
#include <hip/hip_bf16.h>

// Problem constants
#define L_ACT   12
#define BDIM    16
#define PDIM    128
#define DSUM    128
#define HID     512
#define ODIM    2048
#define NHEAD   16
#define DHEAD   64
#define MROWS   2048   // B*P rows per layer

typedef short s16x4  __attribute__((ext_vector_type(4)));
typedef short short8 __attribute__((ext_vector_type(8)));
typedef float f32x4  __attribute__((ext_vector_type(4)));

__device__ __forceinline__ void gload_lds16(const __hip_bfloat16* g, __hip_bfloat16* l) {
  __builtin_amdgcn_global_load_lds(
      (const __attribute__((address_space(1))) unsigned int*)g,
      (__attribute__((address_space(3))) unsigned int*)l, 16, 0, 0);
}

__device__ __forceinline__ short f2bf(float x) {
  __hip_bfloat16 h = __float2bfloat16(x);
  return *reinterpret_cast<short*>(&h);
}

// --- zero-fill (fallback path only) ---
__global__ __launch_bounds__(256) void zerofill_kernel(f32x4* __restrict__ p, int n16) {
  int stride = gridDim.x * 256;
  for (int i = blockIdx.x * 256 + threadIdx.x; i < n16; i += stride)
    p[i] = {0.f, 0.f, 0.f, 0.f};
}

// --- prep_tiny: blocks 0..767 -> W1T transpose; block 768 -> cos/sin table ---
__global__ __launch_bounds__(256) void prep_tiny(
    const int* __restrict__ positions, const float* __restrict__ W1,
    float* __restrict__ cs, __hip_bfloat16* __restrict__ W1T) {
  const int bid = blockIdx.x;
  const int tid = threadIdx.x;
  if (bid == 768) {
#pragma unroll
    for (int q = 0; q < 4; ++q) {
      int i = q * 256 + tid;
      int p = i >> 3, f = i & 7;
      double inv = pow(10000.0, -(double)f / 8.0);
      double ang = (double)positions[p] * inv;
      cs[i]        = (float)cos(ang);
      cs[1024 + i] = (float)sin(ang);
    }
  } else {
    __shared__ float t[32][33];
    int bx = bid & 15, by = (bid >> 4) & 3, l = bid >> 6;   // 16 o-tiles x 4 j-tiles
    int o0 = bx * 32, j0 = by * 32;
    int tx = tid & 31, ty = tid >> 5;   // 32x8
    const float* ip = W1 + (size_t)l * DSUM * HID;
#pragma unroll
    for (int r = 0; r < 32; r += 8)
      t[ty + r][tx] = ip[(size_t)(j0 + ty + r) * HID + o0 + tx];
    __syncthreads();
    __hip_bfloat16* op = W1T + (size_t)l * DSUM * HID;
#pragma unroll
    for (int r = 0; r < 32; r += 8)
      op[(size_t)(o0 + ty + r) * DSUM + j0 + tx] = __float2bfloat16(t[tx][ty + r]);
  }
}

// --- GEMM1: 128x128 tile, 4 waves, bias+relu, bf16 out; A reg-staged
//     directly from summary f32; B via gload_lds from W1T; fused zero-fill. ---
__global__ __launch_bounds__(256) void gemm1_128(
    const float* __restrict__ summary,          // [2048][128] f32
    const __hip_bfloat16* __restrict__ Ball,    // W1T [12][512][128]
    const float* __restrict__ bias,
    __hip_bfloat16* __restrict__ Hall,
    f32x4* __restrict__ zeroBase, int doZero) {
  const int KTOT = DSUM, NTOT = HID;
  __shared__ __hip_bfloat16 ldsA[128 * 64];
  __shared__ __hip_bfloat16 ldsB[128 * 64];
  const int l    = blockIdx.z;
  const int n0   = blockIdx.x * 128;
  const int m0   = blockIdx.y * 128;
  const int tid  = threadIdx.x;
  const int wid  = tid >> 6;
  const int lane = tid & 63;
  const int wr = wid >> 1, wc = wid & 1;
  const __hip_bfloat16* Bt = Ball + (size_t)l * NTOT * KTOT;

  f32x4 acc[4][4];
#pragma unroll
  for (int m = 0; m < 4; ++m)
#pragma unroll
    for (int n = 0; n < 4; ++n)
      acc[m][n] = {0.f, 0.f, 0.f, 0.f};

  const int srowi = lane >> 3;
  const int sblk  = (lane & 7) ^ srowi;

  for (int kt = 0; kt < KTOT / 64; ++kt) {
    __syncthreads();
    // B: async gload_lds (pre-swizzled source), as proven
#pragma unroll
    for (int s = 0; s < 4; ++s) {
      int seg = wid * 4 + s;
      int row = seg * 8 + srowi;
      gload_lds16(Bt + (size_t)(n0 + row) * KTOT + kt * 64 + sblk * 8, ldsB + seg * 512);
    }
    // A: reg-staged f32 -> bf16, swizzled ds_write_b64
#pragma unroll
    for (int j = 0; j < 8; ++j) {
      int s = j * 256 + tid;
      int r = s >> 4, g = s & 15;
      f32x4 v = *(const f32x4*)(summary + (size_t)(m0 + r) * DSUM + kt * 64 + g * 4);
      s16x4 w;
      w[0] = f2bf(v[0]); w[1] = f2bf(v[1]); w[2] = f2bf(v[2]); w[3] = f2bf(v[3]);
      int ch = g >> 1;
      *(s16x4*)((char*)ldsA + r * 128 + ((ch ^ (r & 7)) << 4) + (g & 1) * 8) = w;
    }
    __syncthreads();
#pragma unroll
    for (int kk = 0; kk < 2; ++kk) {
      short8 af[4], bfr[4];
#pragma unroll
      for (int m = 0; m < 4; ++m) {
        int row = wr * 64 + m * 16 + (lane & 15);
        int off = (kk * 64 + (lane >> 4) * 16) ^ ((row & 7) << 4);
        af[m] = *(const short8*)((const char*)ldsA + row * 128 + off);
      }
#pragma unroll
      for (int n = 0; n < 4; ++n) {
        int row = wc * 64 + n * 16 + (lane & 15);
        int off = (kk * 64 + (lane >> 4) * 16) ^ ((row & 7) << 4);
        bfr[n] = *(const short8*)((const char*)ldsB + row * 128 + off);
      }
#pragma unroll
      for (int m = 0; m < 4; ++m)
#pragma unroll
        for (int n = 0; n < 4; ++n)
          acc[m][n] = __builtin_amdgcn_mfma_f32_16x16x32_bf16(af[m], bfr[n], acc[m][n], 0, 0, 0);
    }
  }

  const int bid = blockIdx.x + 4 * blockIdx.y + 64 * blockIdx.z;   // 0..767

  if (doZero) {
    const f32x4 z = {0.f, 0.f, 0.f, 0.f};
    f32x4* zp = zeroBase + (size_t)bid * 16384;                    // 256KB chunk
#pragma unroll
    for (int i = 0; i < 64; ++i)
      __builtin_nontemporal_store(z, zp + i * 256 + tid);
  }

  const int colBase = n0 + wc * 64 + (lane & 15);
  const int rowBase = m0 + wr * 64 + ((lane >> 4) << 2);
  __hip_bfloat16* H = Hall + (size_t)l * MROWS * HID;
#pragma unroll
  for (int n = 0; n < 4; ++n) {
    int col = colBase + n * 16;
    float bb = bias[l * NTOT + col];
#pragma unroll
    for (int m = 0; m < 4; ++m) {
      int row = rowBase + m * 16;
#pragma unroll
      for (int j = 0; j < 4; ++j) {
        float v = acc[m][n][j] + bb;
        v = v > 0.f ? v : 0.f;
        H[(size_t)(row + j) * HID + col] = __float2bfloat16(v);
      }
    }
  }
}

// --- GEMM2: 256x256 tile, 8 waves (2Mx4N), BK=32. A: 4-slot gload_lds ring
//     from h_bf. B: reg-staged DIRECTLY from W2 f32 (k-gather scalar loads,
//     2 iterations ahead, alternating named reg sets), cvt->swizzled
//     ds_write_b128 into a 2-buf LDS region. XCD-chunked swizzle, 16x16x32
//     MFMA, LDS-transpose epilogue with nt 1KB slab stores. ---
__global__ __launch_bounds__(512, 1) void gemm2_pipe(
    const __hip_bfloat16* __restrict__ Aall,   // h_bf [12][2048][512]
    const float* __restrict__ W2,              // [12][512][2048] f32
    const float* __restrict__ bias,            // b2   [12][2048]
    const float* __restrict__ cs,
    float* __restrict__ O) {
  __shared__ __hip_bfloat16 lds[6 * 8192];   // A ring 4x16KB @0, B dbuf 2x16KB @64KB
  const int orig = blockIdx.x + 8 * blockIdx.y + 64 * blockIdx.z;
  const int nw   = (orig & 7) * 96 + (orig >> 3);
  const int bx = nw & 7, by = (nw >> 3) & 7, l = nw >> 6;
  const int n0 = bx * 256, m0 = by * 256;
  const int tid = threadIdx.x;
  const int wid = tid >> 6, lane = tid & 63;
  const int wm  = wid >> 2, wn = wid & 3;
  const __hip_bfloat16* A = Aall + (size_t)l * MROWS * HID;
  const float* W2l = W2 + (size_t)l * HID * ODIM;

  f32x4 acc[8][4];
#pragma unroll
  for (int m = 0; m < 8; ++m)
#pragma unroll
    for (int n = 0; n < 4; ++n)
      acc[m][n] = {0.f, 0.f, 0.f, 0.f};

  // A staging chunks (linear LDS dest, inverse-swizzled global source)
  const int cidx0 = wid * 128 + lane;
  const int cidx1 = cidx0 + 64;
  const int r0 = cidx0 >> 2, c0 = (cidx0 & 3) ^ ((r0 >> 1) & 3);
  const int r1 = cidx1 >> 2, c1 = (cidx1 & 3) ^ ((r1 >> 1) & 3);

#define STAGE_A(slot, kt) do {                                                      \
    gload_lds16(A + (size_t)(m0 + r0) * HID + (kt) * 32 + c0 * 8,                   \
                lds + (slot) * 8192 + wid * 1024);                                  \
    gload_lds16(A + (size_t)(m0 + r1) * HID + (kt) * 32 + c1 * 8,                   \
                lds + (slot) * 8192 + wid * 1024 + 512);                            \
  } while (0)

  // B staging geometry: thread owns n = tid&255, chunks bc and bc+2 (bc=tid>>8)
  const int bn = tid & 255;
  const int bc = tid >> 8;
  const int bswz0 = (bc     ) ^ ((bn >> 1) & 3);
  const int bswz1 = (bc + 2 ) ^ ((bn >> 1) & 3);
  const float* bsrc0 = W2l + (size_t)(bc * 8) * ODIM + n0 + bn;
  const float* bsrc1 = bsrc0 + (size_t)16 * ODIM;

  float b_a0, b_a1, b_a2, b_a3, b_a4, b_a5, b_a6, b_a7,
        b_a8, b_a9, b_a10, b_a11, b_a12, b_a13, b_a14, b_a15;
  float b_b0, b_b1, b_b2, b_b3, b_b4, b_b5, b_b6, b_b7,
        b_b8, b_b9, b_b10, b_b11, b_b12, b_b13, b_b14, b_b15;

#define BLOAD(P, kt) do {                                                           \
    const float* p0_ = bsrc0 + (size_t)(kt) * 32 * ODIM;                            \
    const float* p1_ = bsrc1 + (size_t)(kt) * 32 * ODIM;                            \
    P##0 = p0_[0*ODIM]; P##1 = p0_[1*ODIM]; P##2 = p0_[2*ODIM]; P##3 = p0_[3*ODIM]; \
    P##4 = p0_[4*ODIM]; P##5 = p0_[5*ODIM]; P##6 = p0_[6*ODIM]; P##7 = p0_[7*ODIM]; \
    P##8 = p1_[0*ODIM]; P##9 = p1_[1*ODIM]; P##10 = p1_[2*ODIM]; P##11 = p1_[3*ODIM];\
    P##12 = p1_[4*ODIM]; P##13 = p1_[5*ODIM]; P##14 = p1_[6*ODIM]; P##15 = p1_[7*ODIM];\
  } while (0)

#define BWRITE(P, bufbyte) do {                                                     \
    short8 w0_, w1_;                                                                \
    w0_[0] = f2bf(P##0); w0_[1] = f2bf(P##1); w0_[2] = f2bf(P##2); w0_[3] = f2bf(P##3);\
    w0_[4] = f2bf(P##4); w0_[5] = f2bf(P##5); w0_[6] = f2bf(P##6); w0_[7] = f2bf(P##7);\
    w1_[0] = f2bf(P##8); w1_[1] = f2bf(P##9); w1_[2] = f2bf(P##10); w1_[3] = f2bf(P##11);\
    w1_[4] = f2bf(P##12); w1_[5] = f2bf(P##13); w1_[6] = f2bf(P##14); w1_[7] = f2bf(P##15);\
    *(short8*)((bufbyte) + bn * 64 + bswz0 * 16) = w0_;                             \
    *(short8*)((bufbyte) + bn * 64 + bswz1 * 16) = w1_;                             \
  } while (0)

  const int kq   = lane >> 4;
  const int rl15 = lane & 15;

#define LD_FRAG(dst, base, rr) do {                                                 \
    int r_ = (rr);                                                                  \
    int off_ = r_ * 64 + ((kq ^ ((r_ >> 1) & 3)) << 4);                             \
    dst = *(const short8*)((const char*)(base) + off_);                             \
  } while (0)

  // ---- prologue ----
  BLOAD(b_a, 0);
  __builtin_amdgcn_sched_barrier(0);
  STAGE_A(0, 0); STAGE_A(1, 1); STAGE_A(2, 2);
  __builtin_amdgcn_sched_barrier(0);
  BWRITE(b_a, (char*)lds + 65536);             // Bbuf0 (compiler waits b_a loads)
  __builtin_amdgcn_sched_barrier(0);
  BLOAD(b_b, 1);
  __builtin_amdgcn_sched_barrier(0);
  asm volatile("s_waitcnt vmcnt(16)" ::: "memory");  // A(0..2) landed
  asm volatile("s_waitcnt lgkmcnt(0)" ::: "memory");
  __builtin_amdgcn_s_barrier();

#define ITER_BODY(T, PL, PW) do {                                                   \
    const int t_ = (T);                                                             \
    const char* sa_ = (const char*)lds + (t_ & 3) * 16384;                          \
    const char* sb_ = (const char*)lds + 65536 + (t_ & 1) * 16384;                  \
    short8 af[4], bfr[4];                                                           \
    _Pragma("unroll")                                                               \
    for (int n_ = 0; n_ < 4; ++n_) LD_FRAG(bfr[n_], sb_, wn * 64 + n_ * 16 + rl15); \
    _Pragma("unroll")                                                               \
    for (int mi_ = 0; mi_ < 4; ++mi_) LD_FRAG(af[mi_], sa_, wm * 128 + mi_ * 16 + rl15);\
    if (t_ + 3 < 16) STAGE_A((t_ + 3) & 3, t_ + 3);                                 \
    __builtin_amdgcn_sched_barrier(0);                                              \
    if (t_ + 2 < 16) BLOAD(PL, t_ + 2);                                             \
    __builtin_amdgcn_sched_barrier(0);                                              \
    __builtin_amdgcn_s_barrier();                                                   \
    __builtin_amdgcn_s_setprio(1);                                                  \
    _Pragma("unroll")                                                               \
    for (int mi_ = 0; mi_ < 4; ++mi_)                                               \
      _Pragma("unroll")                                                             \
      for (int n_ = 0; n_ < 4; ++n_)                                                \
        acc[mi_][n_] = __builtin_amdgcn_mfma_f32_16x16x32_bf16(af[mi_], bfr[n_], acc[mi_][n_], 0, 0, 0);\
    __builtin_amdgcn_s_setprio(0);                                                  \
    _Pragma("unroll")                                                               \
    for (int mi_ = 0; mi_ < 4; ++mi_) LD_FRAG(af[mi_], sa_, wm * 128 + 64 + mi_ * 16 + rl15);\
    __builtin_amdgcn_s_setprio(1);                                                  \
    _Pragma("unroll")                                                               \
    for (int mi_ = 0; mi_ < 4; ++mi_)                                               \
      _Pragma("unroll")                                                             \
      for (int n_ = 0; n_ < 4; ++n_)                                                \
        acc[4 + mi_][n_] = __builtin_amdgcn_mfma_f32_16x16x32_bf16(af[mi_], bfr[n_], acc[4 + mi_][n_], 0, 0, 0);\
    __builtin_amdgcn_s_setprio(0);                                                  \
    if (t_ + 1 < 16) {                                                              \
      __builtin_amdgcn_sched_barrier(0);                                            \
      BWRITE(PW, (char*)lds + 65536 + ((t_ + 1) & 1) * 16384);                      \
      asm volatile("s_waitcnt lgkmcnt(0)" ::: "memory");                            \
    }                                                                               \
    __builtin_amdgcn_s_barrier();                                                   \
  } while (0)

  for (int t = 0; t < 16; t += 2) {
    ITER_BODY(t,     b_a, b_b);   // even: load B(t+2)->setA, write B(t+1) from setB
    ITER_BODY(t + 1, b_b, b_a);   // odd: swapped
  }
#undef ITER_BODY
#undef STAGE_A
#undef BLOAD
#undef BWRITE
#undef LD_FRAG

  // ---- epilogue: bias + RoPE in-reg, per-wave LDS transpose, nt 1KB stores ----
  __syncthreads();
  const int head = bx * 2 + (wn >> 1);
  const int tkv  = wn & 1;
  const int bidx = by * 2 + wm;
  float* slab = O + ((((size_t)(l + L_ACT) * 2 + tkv) * BDIM + bidx) * NHEAD + head) * (PDIM * DHEAD);
  const bool ropeWave = (tkv == 0);

  float bb[4];
#pragma unroll
  for (int n = 0; n < 4; ++n) bb[n] = bias[l * ODIM + n0 + wn * 64 + n * 16 + rl15];

  float* Tw = (float*)lds + wid * 2080;   // 32 x 65 f32 per wave

#pragma unroll
  for (int c = 0; c < 4; ++c) {           // p-chunk [c*32, c*32+32)
#pragma unroll
    for (int mh = 0; mh < 2; ++mh) {
      int mf = c * 2 + mh;
      int pl = mh * 16 + (lane >> 4) * 4;
#pragma unroll
      for (int n = 0; n < 4; ++n) {
#pragma unroll
        for (int j = 0; j < 4; ++j) {
          float v = acc[mf][n][j] + bb[n];
          if (ropeWave && n == 0) {
            float partner = __shfl_xor(v, 8);
            int p = c * 32 + pl + j;
            float cv = cs[p * 8 + (lane & 7)];
            float sv = cs[1024 + p * 8 + (lane & 7)];
            v = v * cv + (((lane & 15) < 8) ? -partner : partner) * sv;
          }
          Tw[(pl + j) * 65 + n * 16 + rl15] = v;
        }
      }
    }
#pragma unroll
    for (int it = 0; it < 8; ++it) {
      int pl = it * 4 + (lane >> 4);
      f32x4 vv = *(const f32x4*)(Tw + pl * 65 + rl15 * 4);
      __builtin_nontemporal_store(vv, (f32x4*)(slab + (size_t)(c * 32 + pl) * DHEAD + rl15 * 4));
    }
  }
}

extern "C" void kernel_launch(void* const* d_in, const int* in_sizes, int n_in,
                              void* d_out, int out_size, void* d_ws, size_t ws_size,
                              hipStream_t stream) {
  const float* summary   = (const float*)d_in[0];
  const int*   positions = (const int*)d_in[1];
  const float* W1 = (const float*)d_in[2];
  const float* b1 = (const float*)d_in[3];
  const float* W2 = (const float*)d_in[4];
  const float* b2 = (const float*)d_in[5];
  float* out = (float*)d_out;

  // Scratch: h_bf (25165824 B) + W1T (1572864 B) + cs (8192 B)
  const size_t SCRATCH_BYTES = 25165824 + 1572864 + 8192;
  const bool useWs = (ws_size >= SCRATCH_BYTES);
  char* sc = useWs ? (char*)d_ws : (char*)d_out;
  __hip_bfloat16* h_bf = (__hip_bfloat16*)sc;
  __hip_bfloat16* W1T  = (__hip_bfloat16*)(sc + 25165824);
  float*          cs   = (float*)(sc + 25165824 + 1572864);

  prep_tiny<<<769, 256, 0, stream>>>(positions, W1, cs, W1T);

  gemm1_128<<<dim3(HID / 128, MROWS / 128, L_ACT), 256, 0, stream>>>(
      summary, W1T, b1, h_bf, (f32x4*)d_out, useWs ? 1 : 0);
  gemm2_pipe<<<dim3(ODIM / 256, MROWS / 256, L_ACT), 512, 0, stream>>>(
      h_bf, W2, b2, cs, out);

  if (!useWs)   // scratch aliased d_out: zero AFTER gemm2 has consumed it
    zerofill_kernel<<<2048, 256, 0, stream>>>((f32x4*)d_out, 12582912);
}

// Round 9
// 135.384 us; speedup vs baseline: 1.0815x; 1.0815x over previous
//
#include <hip/hip_runtime.h>
#include <hip/hip_bf16.h>

// Problem constants
#define L_ACT   12
#define BDIM    16
#define PDIM    128
#define DSUM    128
#define HID     512
#define ODIM    2048
#define NHEAD   16
#define DHEAD   64
#define MROWS   2048   // B*P rows per layer

typedef short short8 __attribute__((ext_vector_type(8)));
typedef float f32x4  __attribute__((ext_vector_type(4)));

__device__ __forceinline__ void gload_lds16(const __hip_bfloat16* g, __hip_bfloat16* l) {
  __builtin_amdgcn_global_load_lds(
      (const __attribute__((address_space(1))) unsigned int*)g,
      (__attribute__((address_space(3))) unsigned int*)l, 16, 0, 0);
}

// --- zero-fill (fallback path only) ---
__global__ __launch_bounds__(256) void zerofill_kernel(f32x4* __restrict__ p, int n16) {
  int stride = gridDim.x * 256;
  for (int i = blockIdx.x * 256 + threadIdx.x; i < n16; i += stride)
    p[i] = {0.f, 0.f, 0.f, 0.f};
}

// --- prep_small: A_bf + cs | W1T, by blockIdx range ---
__global__ __launch_bounds__(256) void prep_small(
    const float* __restrict__ summary, const int* __restrict__ positions,
    const float* __restrict__ W1,
    __hip_bfloat16* __restrict__ A_bf, float* __restrict__ cs,
    __hip_bfloat16* __restrict__ W1T) {
  const int bid = blockIdx.x;
  const int tid = threadIdx.x;
  if (bid < 1024) {
    int i = bid * 256 + tid;            // covers 262144 exactly
    A_bf[i] = __float2bfloat16(summary[i]);
    if (i < PDIM * 8) {
      int p = i >> 3, f = i & 7;
      double inv = pow(10000.0, -(double)f / 8.0);
      double ang = (double)positions[p] * inv;
      cs[i]        = (float)cos(ang);
      cs[1024 + i] = (float)sin(ang);
    }
  } else {
    __shared__ float t[32][33];
    int idx = bid - 1024;               // W1: [128][512] -> [512][128], 16x4 tiles x 12
    int bx = idx & 15, by = (idx >> 4) & 3, l = idx >> 6;
    int o0 = bx * 32, j0 = by * 32;
    int tx = tid & 31, ty = tid >> 5;   // 32x8
    const float* ip = W1 + (size_t)l * DSUM * HID;
#pragma unroll
    for (int r = 0; r < 32; r += 8)
      t[ty + r][tx] = ip[(size_t)(j0 + ty + r) * HID + o0 + tx];
    __syncthreads();
    __hip_bfloat16* op = W1T + (size_t)l * DSUM * HID;
#pragma unroll
    for (int r = 0; r < 32; r += 8)
      op[(size_t)(o0 + ty + r) * DSUM + j0 + tx] = __float2bfloat16(t[tx][ty + r]);
  }
}

// --- GEMM1: 128x128 tile, 4 waves, bias+relu, bf16 out; fused zero-fill
//     (768 x 256KB nt chunks) + fused W2 -> W2T transpose; H stored via
//     LDS transpose -> 256B-contiguous short8 runs. ---
__global__ __launch_bounds__(256) void gemm1_128(
    const __hip_bfloat16* __restrict__ Aall,
    const __hip_bfloat16* __restrict__ Ball,
    const float* __restrict__ bias,
    __hip_bfloat16* __restrict__ Hall,
    const float* __restrict__ W2,
    __hip_bfloat16* __restrict__ W2T,
    f32x4* __restrict__ zeroBase, int doZero) {
  const int KTOT = DSUM, NTOT = HID;
  __shared__ __hip_bfloat16 shbuf[17408];   // 34816B: staging 2x16KB | H tile 128x136
  __hip_bfloat16* ldsA = shbuf;
  __hip_bfloat16* ldsB = shbuf + 8192;
  const int l    = blockIdx.z;
  const int n0   = blockIdx.x * 128;
  const int m0   = blockIdx.y * 128;
  const int tid  = threadIdx.x;
  const int wid  = tid >> 6;
  const int lane = tid & 63;
  const int wr = wid >> 1, wc = wid & 1;
  const __hip_bfloat16* A  = Aall;
  const __hip_bfloat16* Bt = Ball + (size_t)l * NTOT * KTOT;

  f32x4 acc[4][4];
#pragma unroll
  for (int m = 0; m < 4; ++m)
#pragma unroll
    for (int n = 0; n < 4; ++n)
      acc[m][n] = {0.f, 0.f, 0.f, 0.f};

  const int srowi = lane >> 3;
  const int sblk  = (lane & 7) ^ srowi;

  for (int kt = 0; kt < KTOT / 64; ++kt) {
    __syncthreads();
#pragma unroll
    for (int s = 0; s < 4; ++s) {
      int seg = wid * 4 + s;
      int row = seg * 8 + srowi;
      gload_lds16(A  + (size_t)(m0 + row) * KTOT + kt * 64 + sblk * 8, ldsA + seg * 512);
      gload_lds16(Bt + (size_t)(n0 + row) * KTOT + kt * 64 + sblk * 8, ldsB + seg * 512);
    }
    __syncthreads();
#pragma unroll
    for (int kk = 0; kk < 2; ++kk) {
      short8 af[4], bfr[4];
#pragma unroll
      for (int m = 0; m < 4; ++m) {
        int row = wr * 64 + m * 16 + (lane & 15);
        int off = (kk * 64 + (lane >> 4) * 16) ^ ((row & 7) << 4);
        af[m] = *(const short8*)((const char*)ldsA + row * 128 + off);
      }
#pragma unroll
      for (int n = 0; n < 4; ++n) {
        int row = wc * 64 + n * 16 + (lane & 15);
        int off = (kk * 64 + (lane >> 4) * 16) ^ ((row & 7) << 4);
        bfr[n] = *(const short8*)((const char*)ldsB + row * 128 + off);
      }
#pragma unroll
      for (int m = 0; m < 4; ++m)
#pragma unroll
        for (int n = 0; n < 4; ++n)
          acc[m][n] = __builtin_amdgcn_mfma_f32_16x16x32_bf16(af[m], bfr[n], acc[m][n], 0, 0, 0);
    }
  }

  const int bid = blockIdx.x + 4 * blockIdx.y + 64 * blockIdx.z;   // 0..767

  // zero-fill chunk (nontemporal, fire-and-forget)
  if (doZero) {
    const f32x4 z = {0.f, 0.f, 0.f, 0.f};
    f32x4* zp = zeroBase + (size_t)bid * 16384;                    // 256KB chunk
#pragma unroll
    for (int i = 0; i < 64; ++i)
      __builtin_nontemporal_store(z, zp + i * 256 + tid);
  }

  // H epilogue via LDS: [128][136] bf16 padded tile -> 256B-run stores
  __syncthreads();   // all waves done reading staging LDS
#pragma unroll
  for (int n = 0; n < 4; ++n) {
    int col = wc * 64 + n * 16 + (lane & 15);
    float bb = bias[l * NTOT + n0 + col];
#pragma unroll
    for (int m = 0; m < 4; ++m) {
      int rowb = wr * 64 + m * 16 + ((lane >> 4) << 2);
#pragma unroll
      for (int j = 0; j < 4; ++j) {
        float v = acc[m][n][j] + bb;
        v = v > 0.f ? v : 0.f;
        shbuf[(rowb + j) * 136 + col] = __float2bfloat16(v);
      }
    }
  }
  __syncthreads();
  {
    __hip_bfloat16* H = Hall + (size_t)l * MROWS * HID;
#pragma unroll
    for (int i = 0; i < 8; ++i) {
      int idx = i * 256 + tid;
      int row = idx >> 4, seg = idx & 15;
      short8 v = *(const short8*)(shbuf + row * 136 + seg * 8);
      *(short8*)(H + (size_t)(m0 + row) * HID + n0 + seg * 8) = v;
    }
  }

  // fused W2 -> W2T transpose: 16 tiles of 32x32 per block (12288 total)
  {
    float* tb = (float*)shbuf;          // 32x33 f32 (4224B)
    const int tx = tid & 31, ty = tid >> 5;
    const int tbase = bid * 16;
#pragma unroll 1
    for (int tt = 0; tt < 16; ++tt) {
      int t = tbase + tt;
      int lz = t >> 10, rem = t & 1023;
      int jt = rem >> 6, ot = rem & 63;   // 16 j-tiles x 64 o-tiles per layer
      int j0 = jt * 32, o0 = ot * 32;
      const float* ip = W2 + (size_t)lz * HID * ODIM;
      __hip_bfloat16* op = W2T + (size_t)lz * HID * ODIM;
      __syncthreads();
#pragma unroll
      for (int r = 0; r < 32; r += 8)
        tb[(ty + r) * 33 + tx] = ip[(size_t)(j0 + ty + r) * ODIM + o0 + tx];
      __syncthreads();
#pragma unroll
      for (int r = 0; r < 32; r += 8)
        op[(size_t)(o0 + ty + r) * HID + j0 + tx] = __float2bfloat16(tb[tx * 33 + ty + r]);
    }
  }
}

// --- GEMM2 (R4/R6-proven): 256x256 tile, 8 waves (2Mx4N), BK=32, 4-slot LDS
//     ring, fine-grained 2-phase/K-tile pipeline with counted vmcnt, 16x16x32
//     MFMA, XCD-chunked tile swizzle, LDS-transpose epilogue, nt 1KB stores. ---
__global__ __launch_bounds__(512, 1) void gemm2_pipe(
    const __hip_bfloat16* __restrict__ Aall,   // h_bf [12][2048][512]
    const __hip_bfloat16* __restrict__ Ball,   // W2T  [12][2048][512]
    const float* __restrict__ bias,            // b2   [12][2048]
    const float* __restrict__ cs,
    float* __restrict__ O) {
  __shared__ __hip_bfloat16 lds[4 * 16384];    // 128 KiB
  const int orig = blockIdx.x + 8 * blockIdx.y + 64 * blockIdx.z;
  const int nw   = (orig & 7) * 96 + (orig >> 3);
  const int bx   = nw & 7;
  const int by   = (nw >> 3) & 7;
  const int l    = nw >> 6;
  const int n0  = bx * 256;
  const int m0  = by * 256;
  const int tid = threadIdx.x;
  const int wid = tid >> 6, lane = tid & 63;
  const int wm  = wid >> 2, wn = wid & 3;
  const __hip_bfloat16* A  = Aall + (size_t)l * MROWS * HID;
  const __hip_bfloat16* Bt = Ball + (size_t)l * ODIM * HID;

  f32x4 acc[8][4];
#pragma unroll
  for (int m = 0; m < 8; ++m)
#pragma unroll
    for (int n = 0; n < 4; ++n)
      acc[m][n] = {0.f, 0.f, 0.f, 0.f};

  const int cidx0 = wid * 128 + lane;
  const int cidx1 = cidx0 + 64;
  const int r0 = cidx0 >> 2, c0 = (cidx0 & 3) ^ ((r0 >> 1) & 3);
  const int r1 = cidx1 >> 2, c1 = (cidx1 & 3) ^ ((r1 >> 1) & 3);

#define STAGE_A(slot, kt) do {                                                      \
    gload_lds16(A + (size_t)(m0 + r0) * HID + (kt) * 32 + c0 * 8,                   \
                lds + (slot) * 16384 + wid * 1024);                                 \
    gload_lds16(A + (size_t)(m0 + r1) * HID + (kt) * 32 + c1 * 8,                   \
                lds + (slot) * 16384 + wid * 1024 + 512);                           \
  } while (0)
#define STAGE_B(slot, kt) do {                                                      \
    gload_lds16(Bt + (size_t)(n0 + r0) * HID + (kt) * 32 + c0 * 8,                  \
                lds + (slot) * 16384 + 8192 + wid * 1024);                          \
    gload_lds16(Bt + (size_t)(n0 + r1) * HID + (kt) * 32 + c1 * 8,                  \
                lds + (slot) * 16384 + 8192 + wid * 1024 + 512);                    \
  } while (0)

  const int kq   = lane >> 4;
  const int rl15 = lane & 15;

#define LD_FRAG(dst, base, rr) do {                                                 \
    int r_ = (rr);                                                                  \
    int off_ = r_ * 64 + ((kq ^ ((r_ >> 1) & 3)) << 4);                             \
    dst = *(const short8*)((const char*)(base) + off_);                             \
  } while (0)

  // prologue: 3 tiles in flight
  STAGE_A(0, 0); STAGE_B(0, 0);
  STAGE_A(1, 1); STAGE_B(1, 1);
  STAGE_A(2, 2); STAGE_B(2, 2);
  asm volatile("s_waitcnt vmcnt(8)" ::: "memory");
  __builtin_amdgcn_s_barrier();

  const int NT = HID / 32;   // 16
  for (int t = 0; t < NT; ++t) {
    const __hip_bfloat16* sa = lds + (t & 3) * 16384;
    const __hip_bfloat16* sb = sa + 8192;
    short8 af[4], bfr[4];

    // ---- phase 0: m-frags 0..3 ----
#pragma unroll
    for (int n = 0; n < 4; ++n) LD_FRAG(bfr[n], sb, wn * 64 + n * 16 + rl15);
#pragma unroll
    for (int mi = 0; mi < 4; ++mi) LD_FRAG(af[mi], sa, wm * 128 + mi * 16 + rl15);
    if (t + 3 < NT) STAGE_A((t + 3) & 3, t + 3);
    __builtin_amdgcn_s_barrier();
    __builtin_amdgcn_s_setprio(1);
#pragma unroll
    for (int mi = 0; mi < 4; ++mi)
#pragma unroll
      for (int n = 0; n < 4; ++n)
        acc[mi][n] = __builtin_amdgcn_mfma_f32_16x16x32_bf16(af[mi], bfr[n], acc[mi][n], 0, 0, 0);
    __builtin_amdgcn_s_setprio(0);
    __builtin_amdgcn_s_barrier();

    // ---- phase 1: m-frags 4..7 (bfr reused) ----
#pragma unroll
    for (int mi = 0; mi < 4; ++mi) LD_FRAG(af[mi], sa, wm * 128 + 64 + mi * 16 + rl15);
    if (t + 3 < NT) STAGE_B((t + 3) & 3, t + 3);
    __builtin_amdgcn_s_barrier();
    __builtin_amdgcn_s_setprio(1);
#pragma unroll
    for (int mi = 0; mi < 4; ++mi)
#pragma unroll
      for (int n = 0; n < 4; ++n)
        acc[4 + mi][n] = __builtin_amdgcn_mfma_f32_16x16x32_bf16(af[mi], bfr[n], acc[4 + mi][n], 0, 0, 0);
    __builtin_amdgcn_s_setprio(0);
    if (t < NT - 1) {
      if (t <= NT - 4)      asm volatile("s_waitcnt vmcnt(8)" ::: "memory");
      else if (t == NT - 3) asm volatile("s_waitcnt vmcnt(4)" ::: "memory");
      else                  asm volatile("s_waitcnt vmcnt(0)" ::: "memory");
    }
    __builtin_amdgcn_s_barrier();
  }
#undef STAGE_A
#undef STAGE_B
#undef LD_FRAG

  // ---- epilogue: bias + RoPE in-reg, per-wave LDS transpose, nt 1KB stores ----
  __syncthreads();
  const int head = bx * 2 + (wn >> 1);
  const int tkv  = wn & 1;
  const int bidx = by * 2 + wm;
  float* slab = O + ((((size_t)(l + L_ACT) * 2 + tkv) * BDIM + bidx) * NHEAD + head) * (PDIM * DHEAD);
  const bool ropeWave = (tkv == 0);

  float bb[4];
#pragma unroll
  for (int n = 0; n < 4; ++n) bb[n] = bias[l * ODIM + n0 + wn * 64 + n * 16 + rl15];

  float* Tw = (float*)lds + wid * 2080;   // 32 x 65 f32 per wave

#pragma unroll
  for (int c = 0; c < 4; ++c) {           // p-chunk [c*32, c*32+32)
#pragma unroll
    for (int mh = 0; mh < 2; ++mh) {
      int mf = c * 2 + mh;
      int pl = mh * 16 + (lane >> 4) * 4;
#pragma unroll
      for (int n = 0; n < 4; ++n) {
#pragma unroll
        for (int j = 0; j < 4; ++j) {
          float v = acc[mf][n][j] + bb[n];
          if (ropeWave && n == 0) {
            float partner = __shfl_xor(v, 8);
            int p = c * 32 + pl + j;
            float cv = cs[p * 8 + (lane & 7)];
            float sv = cs[1024 + p * 8 + (lane & 7)];
            v = v * cv + (((lane & 15) < 8) ? -partner : partner) * sv;
          }
          Tw[(pl + j) * 65 + n * 16 + rl15] = v;
        }
      }
    }
#pragma unroll
    for (int it = 0; it < 8; ++it) {
      int pl = it * 4 + (lane >> 4);
      f32x4 vv = *(const f32x4*)(Tw + pl * 65 + rl15 * 4);
      __builtin_nontemporal_store(vv, (f32x4*)(slab + (size_t)(c * 32 + pl) * DHEAD + rl15 * 4));
    }
  }
}

extern "C" void kernel_launch(void* const* d_in, const int* in_sizes, int n_in,
                              void* d_out, int out_size, void* d_ws, size_t ws_size,
                              hipStream_t stream) {
  const float* summary   = (const float*)d_in[0];
  const int*   positions = (const int*)d_in[1];
  const float* W1 = (const float*)d_in[2];
  const float* b1 = (const float*)d_in[3];
  const float* W2 = (const float*)d_in[4];
  const float* b2 = (const float*)d_in[5];
  float* out = (float*)d_out;

  const size_t SCRATCH_BYTES = 52436992;
  const bool useWs = (ws_size >= SCRATCH_BYTES);
  char* sc = useWs ? (char*)d_ws : (char*)d_out;
  __hip_bfloat16* h_bf = (__hip_bfloat16*)sc;                    // 25165824 B
  __hip_bfloat16* W2T  = (__hip_bfloat16*)(sc + 25165824);       // 25165824 B
  __hip_bfloat16* W1T  = (__hip_bfloat16*)(sc + 50331648);       // 1572864 B
  __hip_bfloat16* A_bf = (__hip_bfloat16*)(sc + 51904512);       // 524288 B
  float*          cs   = (float*)(sc + 52428800);                // 8192 B

  prep_small<<<1792, 256, 0, stream>>>(summary, positions, W1, A_bf, cs, W1T);

  gemm1_128<<<dim3(HID / 128, MROWS / 128, L_ACT), 256, 0, stream>>>(
      A_bf, W1T, b1, h_bf, W2, W2T, (f32x4*)d_out, useWs ? 1 : 0);
  gemm2_pipe<<<dim3(ODIM / 256, MROWS / 256, L_ACT), 512, 0, stream>>>(h_bf, W2T, b2, cs, out);

  if (!useWs)   // scratch aliased d_out: zero AFTER gemm2 has consumed it
    zerofill_kernel<<<2048, 256, 0, stream>>>((f32x4*)d_out, 12582912);
}

// Round 10
// 129.923 us; speedup vs baseline: 1.1270x; 1.0420x over previous
//
#include <hip/hip_runtime.h>
#include <hip/hip_bf16.h>

// Problem constants
#define L_ACT   12
#define BDIM    16
#define PDIM    128
#define DSUM    128
#define HID     512
#define ODIM    2048
#define NHEAD   16
#define DHEAD   64
#define MROWS   2048   // B*P rows per layer

typedef short s16x4  __attribute__((ext_vector_type(4)));
typedef short short8 __attribute__((ext_vector_type(8)));
typedef float f32x4  __attribute__((ext_vector_type(4)));

__device__ __forceinline__ void gload_lds16(const __hip_bfloat16* g, __hip_bfloat16* l) {
  __builtin_amdgcn_global_load_lds(
      (const __attribute__((address_space(1))) unsigned int*)g,
      (__attribute__((address_space(3))) unsigned int*)l, 16, 0, 0);
}

__device__ __forceinline__ short f2bf(float x) {
  __hip_bfloat16 h = __float2bfloat16(x);
  return *reinterpret_cast<short*>(&h);
}

// --- zero-fill (fallback path only) ---
__global__ __launch_bounds__(256) void zerofill_kernel(f32x4* __restrict__ p, int n16) {
  int stride = gridDim.x * 256;
  for (int i = blockIdx.x * 256 + threadIdx.x; i < n16; i += stride)
    p[i] = {0.f, 0.f, 0.f, 0.f};
}

// --- prep_tiny: blocks 0..767 -> W1T transpose; block 768 -> cos/sin table ---
__global__ __launch_bounds__(256) void prep_tiny(
    const int* __restrict__ positions, const float* __restrict__ W1,
    float* __restrict__ cs, __hip_bfloat16* __restrict__ W1T) {
  const int bid = blockIdx.x;
  const int tid = threadIdx.x;
  if (bid == 768) {
#pragma unroll
    for (int q = 0; q < 4; ++q) {
      int i = q * 256 + tid;
      int p = i >> 3, f = i & 7;
      double inv = pow(10000.0, -(double)f / 8.0);
      double ang = (double)positions[p] * inv;
      cs[i]        = (float)cos(ang);
      cs[1024 + i] = (float)sin(ang);
    }
  } else {
    __shared__ float t[32][33];
    int bx = bid & 15, by = (bid >> 4) & 3, l = bid >> 6;   // 16 o-tiles x 4 j-tiles
    int o0 = bx * 32, j0 = by * 32;
    int tx = tid & 31, ty = tid >> 5;   // 32x8
    const float* ip = W1 + (size_t)l * DSUM * HID;
#pragma unroll
    for (int r = 0; r < 32; r += 8)
      t[ty + r][tx] = ip[(size_t)(j0 + ty + r) * HID + o0 + tx];
    __syncthreads();
    __hip_bfloat16* op = W1T + (size_t)l * DSUM * HID;
#pragma unroll
    for (int r = 0; r < 32; r += 8)
      op[(size_t)(o0 + ty + r) * DSUM + j0 + tx] = __float2bfloat16(t[tx][ty + r]);
  }
}

// --- GEMM1: 128x128 tile, 4 waves, bias+relu, bf16 out. A staged directly
//     from f32 summary (reg cvt + swizzled ds_write); B via gload_lds from
//     W1T; H via LDS transpose -> 256B-contiguous short8 runs; fused
//     PIPELINED W2 -> W2T transpose with interleaved nt zero-fill. ---
__global__ __launch_bounds__(256) void gemm1_128(
    const float* __restrict__ summary,          // [2048][128] f32
    const __hip_bfloat16* __restrict__ Ball,    // W1T [12][512][128]
    const float* __restrict__ bias,
    __hip_bfloat16* __restrict__ Hall,
    const float* __restrict__ W2,
    __hip_bfloat16* __restrict__ W2T,
    f32x4* __restrict__ zeroBase, int doZero) {
  const int KTOT = DSUM, NTOT = HID;
  __shared__ __hip_bfloat16 shbuf[17408];   // 34816B: staging 2x16KB | H 128x136 | W2 dbuf
  __hip_bfloat16* ldsA = shbuf;
  __hip_bfloat16* ldsB = shbuf + 8192;
  const int l    = blockIdx.z;
  const int n0   = blockIdx.x * 128;
  const int m0   = blockIdx.y * 128;
  const int tid  = threadIdx.x;
  const int wid  = tid >> 6;
  const int lane = tid & 63;
  const int wr = wid >> 1, wc = wid & 1;
  const __hip_bfloat16* Bt = Ball + (size_t)l * NTOT * KTOT;

  f32x4 acc[4][4];
#pragma unroll
  for (int m = 0; m < 4; ++m)
#pragma unroll
    for (int n = 0; n < 4; ++n)
      acc[m][n] = {0.f, 0.f, 0.f, 0.f};

  const int srowi = lane >> 3;
  const int sblk  = (lane & 7) ^ srowi;

  for (int kt = 0; kt < KTOT / 64; ++kt) {
    __syncthreads();
    // B: async gload_lds (pre-swizzled source)
#pragma unroll
    for (int s = 0; s < 4; ++s) {
      int seg = wid * 4 + s;
      int row = seg * 8 + srowi;
      gload_lds16(Bt + (size_t)(n0 + row) * KTOT + kt * 64 + sblk * 8, ldsB + seg * 512);
    }
    // A: reg-staged f32 -> bf16, swizzled ds_write_b64 (summary is L2/L3-hot)
#pragma unroll
    for (int j = 0; j < 8; ++j) {
      int s = j * 256 + tid;
      int r = s >> 4, g = s & 15;
      f32x4 v = *(const f32x4*)(summary + (size_t)(m0 + r) * DSUM + kt * 64 + g * 4);
      s16x4 w;
      w[0] = f2bf(v[0]); w[1] = f2bf(v[1]); w[2] = f2bf(v[2]); w[3] = f2bf(v[3]);
      int ch = g >> 1;
      *(s16x4*)((char*)ldsA + r * 128 + ((ch ^ (r & 7)) << 4) + (g & 1) * 8) = w;
    }
    __syncthreads();
#pragma unroll
    for (int kk = 0; kk < 2; ++kk) {
      short8 af[4], bfr[4];
#pragma unroll
      for (int m = 0; m < 4; ++m) {
        int row = wr * 64 + m * 16 + (lane & 15);
        int off = (kk * 64 + (lane >> 4) * 16) ^ ((row & 7) << 4);
        af[m] = *(const short8*)((const char*)ldsA + row * 128 + off);
      }
#pragma unroll
      for (int n = 0; n < 4; ++n) {
        int row = wc * 64 + n * 16 + (lane & 15);
        int off = (kk * 64 + (lane >> 4) * 16) ^ ((row & 7) << 4);
        bfr[n] = *(const short8*)((const char*)ldsB + row * 128 + off);
      }
#pragma unroll
      for (int m = 0; m < 4; ++m)
#pragma unroll
        for (int n = 0; n < 4; ++n)
          acc[m][n] = __builtin_amdgcn_mfma_f32_16x16x32_bf16(af[m], bfr[n], acc[m][n], 0, 0, 0);
    }
  }

  const int bid = blockIdx.x + 4 * blockIdx.y + 64 * blockIdx.z;   // 0..767

  // H epilogue via LDS: [128][136] bf16 padded tile -> 256B-run stores
  __syncthreads();   // all waves done reading staging LDS
#pragma unroll
  for (int n = 0; n < 4; ++n) {
    int col = wc * 64 + n * 16 + (lane & 15);
    float bb = bias[l * NTOT + n0 + col];
#pragma unroll
    for (int m = 0; m < 4; ++m) {
      int rowb = wr * 64 + m * 16 + ((lane >> 4) << 2);
#pragma unroll
      for (int j = 0; j < 4; ++j) {
        float v = acc[m][n][j] + bb;
        v = v > 0.f ? v : 0.f;
        shbuf[(rowb + j) * 136 + col] = __float2bfloat16(v);
      }
    }
  }
  __syncthreads();
  {
    __hip_bfloat16* H = Hall + (size_t)l * MROWS * HID;
#pragma unroll
    for (int i = 0; i < 8; ++i) {
      int idx = i * 256 + tid;
      int row = idx >> 4, seg = idx & 15;
      short8 v = *(const short8*)(shbuf + row * 136 + seg * 8);
      *(short8*)(H + (size_t)(m0 + row) * HID + n0 + seg * 8) = v;
    }
  }

  // fused W2 -> W2T transpose, pipelined (dbuf LDS, 2-deep reg prefetch,
  // 1 barrier/tile) with interleaved nt zero-fill (4 stores/tile).
  {
    float* tb0 = (float*)shbuf;            // 32x33 f32 = 4224B
    float* tb1 = (float*)shbuf + 1056;
    const int tx = tid & 31, ty = tid >> 5;
    const int tbase = bid * 16;
    const f32x4 z = {0.f, 0.f, 0.f, 0.f};
    f32x4* zp = zeroBase + (size_t)bid * 16384;   // 256KB chunk
    float rvA0, rvA1, rvA2, rvA3, rvB0, rvB1, rvB2, rvB3;

#define W2_LOAD(P, tt_) do {                                                \
      int t_ = tbase + (tt_);                                               \
      int lz_ = t_ >> 10, rem_ = t_ & 1023;                                 \
      int j0_ = (rem_ >> 6) * 32, o0_ = (rem_ & 63) * 32;                   \
      const float* ip_ = W2 + (size_t)lz_ * HID * ODIM                      \
                       + (size_t)(j0_ + ty) * ODIM + o0_ + tx;              \
      P##0 = ip_[0];                                                        \
      P##1 = ip_[(size_t)8 * ODIM];                                         \
      P##2 = ip_[(size_t)16 * ODIM];                                        \
      P##3 = ip_[(size_t)24 * ODIM];                                        \
    } while (0)

#define W2_WRITE(buf, P) do {                                               \
      (buf)[(ty +  0) * 33 + tx] = P##0;                                    \
      (buf)[(ty +  8) * 33 + tx] = P##1;                                    \
      (buf)[(ty + 16) * 33 + tx] = P##2;                                    \
      (buf)[(ty + 24) * 33 + tx] = P##3;                                    \
    } while (0)

#define W2_STORE(buf, tt_) do {                                             \
      int t_ = tbase + (tt_);                                               \
      int lz_ = t_ >> 10, rem_ = t_ & 1023;                                 \
      int j0_ = (rem_ >> 6) * 32, o0_ = (rem_ & 63) * 32;                   \
      __hip_bfloat16* op_ = W2T + (size_t)lz_ * HID * ODIM;                 \
      _Pragma("unroll")                                                     \
      for (int r_ = 0; r_ < 4; ++r_)                                        \
        op_[(size_t)(o0_ + ty + 8 * r_) * HID + j0_ + tx] =                 \
            __float2bfloat16((buf)[tx * 33 + ty + 8 * r_]);                 \
    } while (0)

#define ZCHUNK(tt_) do { if (doZero) {                                      \
      _Pragma("unroll")                                                     \
      for (int q_ = 0; q_ < 4; ++q_)                                        \
        __builtin_nontemporal_store(z, zp + ((tt_) * 4 + q_) * 256 + tid);  \
    } } while (0)

    W2_LOAD(rvA, 0);
    W2_LOAD(rvB, 1);
    W2_WRITE(tb0, rvA);
    __syncthreads();
#pragma unroll 1
    for (int tt = 0; tt < 16; tt += 2) {
      // even tile tt: out from tb0; tb1 <- rvB(tt+1); prefetch rvA(tt+2)
      if (tt + 2 < 16) W2_LOAD(rvA, tt + 2);
      W2_STORE(tb0, tt);
      W2_WRITE(tb1, rvB);
      ZCHUNK(tt);
      __syncthreads();
      // odd tile tt+1: out from tb1; tb0 <- rvA(tt+2); prefetch rvB(tt+3)
      if (tt + 3 < 16) W2_LOAD(rvB, tt + 3);
      W2_STORE(tb1, tt + 1);
      if (tt + 2 < 16) W2_WRITE(tb0, rvA);
      ZCHUNK(tt + 1);
      __syncthreads();
    }
#undef W2_LOAD
#undef W2_WRITE
#undef W2_STORE
#undef ZCHUNK
  }
}

// --- GEMM2 (proven): 256x256 tile, 8 waves (2Mx4N), BK=32, 4-slot LDS ring,
//     fine-grained 2-phase/K-tile pipeline with counted vmcnt, 16x16x32 MFMA,
//     XCD-chunked tile swizzle, LDS-transpose epilogue, nt 1KB slab stores. ---
__global__ __launch_bounds__(512, 1) void gemm2_pipe(
    const __hip_bfloat16* __restrict__ Aall,   // h_bf [12][2048][512]
    const __hip_bfloat16* __restrict__ Ball,   // W2T  [12][2048][512]
    const float* __restrict__ bias,            // b2   [12][2048]
    const float* __restrict__ cs,
    float* __restrict__ O) {
  __shared__ __hip_bfloat16 lds[4 * 16384];    // 128 KiB
  const int orig = blockIdx.x + 8 * blockIdx.y + 64 * blockIdx.z;
  const int nw   = (orig & 7) * 96 + (orig >> 3);
  const int bx   = nw & 7;
  const int by   = (nw >> 3) & 7;
  const int l    = nw >> 6;
  const int n0  = bx * 256;
  const int m0  = by * 256;
  const int tid = threadIdx.x;
  const int wid = tid >> 6, lane = tid & 63;
  const int wm  = wid >> 2, wn = wid & 3;
  const __hip_bfloat16* A  = Aall + (size_t)l * MROWS * HID;
  const __hip_bfloat16* Bt = Ball + (size_t)l * ODIM * HID;

  f32x4 acc[8][4];
#pragma unroll
  for (int m = 0; m < 8; ++m)
#pragma unroll
    for (int n = 0; n < 4; ++n)
      acc[m][n] = {0.f, 0.f, 0.f, 0.f};

  const int cidx0 = wid * 128 + lane;
  const int cidx1 = cidx0 + 64;
  const int r0 = cidx0 >> 2, c0 = (cidx0 & 3) ^ ((r0 >> 1) & 3);
  const int r1 = cidx1 >> 2, c1 = (cidx1 & 3) ^ ((r1 >> 1) & 3);

#define STAGE_A(slot, kt) do {                                                      \
    gload_lds16(A + (size_t)(m0 + r0) * HID + (kt) * 32 + c0 * 8,                   \
                lds + (slot) * 16384 + wid * 1024);                                 \
    gload_lds16(A + (size_t)(m0 + r1) * HID + (kt) * 32 + c1 * 8,                   \
                lds + (slot) * 16384 + wid * 1024 + 512);                           \
  } while (0)
#define STAGE_B(slot, kt) do {                                                      \
    gload_lds16(Bt + (size_t)(n0 + r0) * HID + (kt) * 32 + c0 * 8,                  \
                lds + (slot) * 16384 + 8192 + wid * 1024);                          \
    gload_lds16(Bt + (size_t)(n0 + r1) * HID + (kt) * 32 + c1 * 8,                  \
                lds + (slot) * 16384 + 8192 + wid * 1024 + 512);                    \
  } while (0)

  const int kq   = lane >> 4;
  const int rl15 = lane & 15;

#define LD_FRAG(dst, base, rr) do {                                                 \
    int r_ = (rr);                                                                  \
    int off_ = r_ * 64 + ((kq ^ ((r_ >> 1) & 3)) << 4);                             \
    dst = *(const short8*)((const char*)(base) + off_);                             \
  } while (0)

  // prologue: 3 tiles in flight
  STAGE_A(0, 0); STAGE_B(0, 0);
  STAGE_A(1, 1); STAGE_B(1, 1);
  STAGE_A(2, 2); STAGE_B(2, 2);
  asm volatile("s_waitcnt vmcnt(8)" ::: "memory");
  __builtin_amdgcn_s_barrier();

  const int NT = HID / 32;   // 16
  for (int t = 0; t < NT; ++t) {
    const __hip_bfloat16* sa = lds + (t & 3) * 16384;
    const __hip_bfloat16* sb = sa + 8192;
    short8 af[4], bfr[4];

    // ---- phase 0: m-frags 0..3 ----
#pragma unroll
    for (int n = 0; n < 4; ++n) LD_FRAG(bfr[n], sb, wn * 64 + n * 16 + rl15);
#pragma unroll
    for (int mi = 0; mi < 4; ++mi) LD_FRAG(af[mi], sa, wm * 128 + mi * 16 + rl15);
    if (t + 3 < NT) STAGE_A((t + 3) & 3, t + 3);
    __builtin_amdgcn_s_barrier();
    __builtin_amdgcn_s_setprio(1);
#pragma unroll
    for (int mi = 0; mi < 4; ++mi)
#pragma unroll
      for (int n = 0; n < 4; ++n)
        acc[mi][n] = __builtin_amdgcn_mfma_f32_16x16x32_bf16(af[mi], bfr[n], acc[mi][n], 0, 0, 0);
    __builtin_amdgcn_s_setprio(0);
    __builtin_amdgcn_s_barrier();

    // ---- phase 1: m-frags 4..7 (bfr reused) ----
#pragma unroll
    for (int mi = 0; mi < 4; ++mi) LD_FRAG(af[mi], sa, wm * 128 + 64 + mi * 16 + rl15);
    if (t + 3 < NT) STAGE_B((t + 3) & 3, t + 3);
    __builtin_amdgcn_s_barrier();
    __builtin_amdgcn_s_setprio(1);
#pragma unroll
    for (int mi = 0; mi < 4; ++mi)
#pragma unroll
      for (int n = 0; n < 4; ++n)
        acc[4 + mi][n] = __builtin_amdgcn_mfma_f32_16x16x32_bf16(af[mi], bfr[n], acc[4 + mi][n], 0, 0, 0);
    __builtin_amdgcn_s_setprio(0);
    if (t < NT - 1) {
      if (t <= NT - 4)      asm volatile("s_waitcnt vmcnt(8)" ::: "memory");
      else if (t == NT - 3) asm volatile("s_waitcnt vmcnt(4)" ::: "memory");
      else                  asm volatile("s_waitcnt vmcnt(0)" ::: "memory");
    }
    __builtin_amdgcn_s_barrier();
  }
#undef STAGE_A
#undef STAGE_B
#undef LD_FRAG

  // ---- epilogue: bias + RoPE in-reg, per-wave LDS transpose, nt 1KB stores ----
  __syncthreads();
  const int head = bx * 2 + (wn >> 1);
  const int tkv  = wn & 1;
  const int bidx = by * 2 + wm;
  float* slab = O + ((((size_t)(l + L_ACT) * 2 + tkv) * BDIM + bidx) * NHEAD + head) * (PDIM * DHEAD);
  const bool ropeWave = (tkv == 0);

  float bb[4];
#pragma unroll
  for (int n = 0; n < 4; ++n) bb[n] = bias[l * ODIM + n0 + wn * 64 + n * 16 + rl15];

  float* Tw = (float*)lds + wid * 2080;   // 32 x 65 f32 per wave

#pragma unroll
  for (int c = 0; c < 4; ++c) {           // p-chunk [c*32, c*32+32)
#pragma unroll
    for (int mh = 0; mh < 2; ++mh) {
      int mf = c * 2 + mh;
      int pl = mh * 16 + (lane >> 4) * 4;
#pragma unroll
      for (int n = 0; n < 4; ++n) {
#pragma unroll
        for (int j = 0; j < 4; ++j) {
          float v = acc[mf][n][j] + bb[n];
          if (ropeWave && n == 0) {
            float partner = __shfl_xor(v, 8);
            int p = c * 32 + pl + j;
            float cv = cs[p * 8 + (lane & 7)];
            float sv = cs[1024 + p * 8 + (lane & 7)];
            v = v * cv + (((lane & 15) < 8) ? -partner : partner) * sv;
          }
          Tw[(pl + j) * 65 + n * 16 + rl15] = v;
        }
      }
    }
#pragma unroll
    for (int it = 0; it < 8; ++it) {
      int pl = it * 4 + (lane >> 4);
      f32x4 vv = *(const f32x4*)(Tw + pl * 65 + rl15 * 4);
      __builtin_nontemporal_store(vv, (f32x4*)(slab + (size_t)(c * 32 + pl) * DHEAD + rl15 * 4));
    }
  }
}

extern "C" void kernel_launch(void* const* d_in, const int* in_sizes, int n_in,
                              void* d_out, int out_size, void* d_ws, size_t ws_size,
                              hipStream_t stream) {
  const float* summary   = (const float*)d_in[0];
  const int*   positions = (const int*)d_in[1];
  const float* W1 = (const float*)d_in[2];
  const float* b1 = (const float*)d_in[3];
  const float* W2 = (const float*)d_in[4];
  const float* b2 = (const float*)d_in[5];
  float* out = (float*)d_out;

  // Scratch: h_bf 25165824 | W2T 25165824 | W1T 1572864 | cs 8192
  const size_t SCRATCH_BYTES = 25165824ULL + 25165824ULL + 1572864ULL + 8192ULL;
  const bool useWs = (ws_size >= SCRATCH_BYTES);
  char* sc = useWs ? (char*)d_ws : (char*)d_out;
  __hip_bfloat16* h_bf = (__hip_bfloat16*)sc;
  __hip_bfloat16* W2T  = (__hip_bfloat16*)(sc + 25165824);
  __hip_bfloat16* W1T  = (__hip_bfloat16*)(sc + 50331648);
  float*          cs   = (float*)(sc + 51904512);

  prep_tiny<<<769, 256, 0, stream>>>(positions, W1, cs, W1T);

  gemm1_128<<<dim3(HID / 128, MROWS / 128, L_ACT), 256, 0, stream>>>(
      summary, W1T, b1, h_bf, W2, W2T, (f32x4*)d_out, useWs ? 1 : 0);
  gemm2_pipe<<<dim3(ODIM / 256, MROWS / 256, L_ACT), 512, 0, stream>>>(h_bf, W2T, b2, cs, out);

  if (!useWs)   // scratch aliased d_out: zero AFTER gemm2 has consumed it
    zerofill_kernel<<<2048, 256, 0, stream>>>((f32x4*)d_out, 12582912);
}

// Round 11
// 127.785 us; speedup vs baseline: 1.1458x; 1.0167x over previous
//
#include <hip/hip_runtime.h>
#include <hip/hip_bf16.h>

// Problem constants
#define L_ACT   12
#define BDIM    16
#define PDIM    128
#define DSUM    128
#define HID     512
#define ODIM    2048
#define NHEAD   16
#define DHEAD   64
#define MROWS   2048   // B*P rows per layer

typedef short s16x4  __attribute__((ext_vector_type(4)));
typedef short short8 __attribute__((ext_vector_type(8)));
typedef float f32x4  __attribute__((ext_vector_type(4)));

__device__ __forceinline__ void gload_lds16(const __hip_bfloat16* g, __hip_bfloat16* l) {
  __builtin_amdgcn_global_load_lds(
      (const __attribute__((address_space(1))) unsigned int*)g,
      (__attribute__((address_space(3))) unsigned int*)l, 16, 0, 0);
}

__device__ __forceinline__ short f2bf(float x) {
  __hip_bfloat16 h = __float2bfloat16(x);
  return *reinterpret_cast<short*>(&h);
}

// --- zero-fill (fallback path only) ---
__global__ __launch_bounds__(256) void zerofill_kernel(f32x4* __restrict__ p, int n16) {
  int stride = gridDim.x * 256;
  for (int i = blockIdx.x * 256 + threadIdx.x; i < n16; i += stride)
    p[i] = {0.f, 0.f, 0.f, 0.f};
}

// --- prep_tiny: blocks 0..767 -> W1T transpose; block 768 -> cos/sin table ---
__global__ __launch_bounds__(256) void prep_tiny(
    const int* __restrict__ positions, const float* __restrict__ W1,
    float* __restrict__ cs, __hip_bfloat16* __restrict__ W1T) {
  const int bid = blockIdx.x;
  const int tid = threadIdx.x;
  if (bid == 768) {
#pragma unroll
    for (int q = 0; q < 4; ++q) {
      int i = q * 256 + tid;
      int p = i >> 3, f = i & 7;
      double inv = pow(10000.0, -(double)f / 8.0);
      double ang = (double)positions[p] * inv;
      cs[i]        = (float)cos(ang);
      cs[1024 + i] = (float)sin(ang);
    }
  } else {
    __shared__ float t[32][33];
    int bx = bid & 15, by = (bid >> 4) & 3, l = bid >> 6;   // 16 o-tiles x 4 j-tiles
    int o0 = bx * 32, j0 = by * 32;
    int tx = tid & 31, ty = tid >> 5;   // 32x8
    const float* ip = W1 + (size_t)l * DSUM * HID;
#pragma unroll
    for (int r = 0; r < 32; r += 8)
      t[ty + r][tx] = ip[(size_t)(j0 + ty + r) * HID + o0 + tx];
    __syncthreads();
    __hip_bfloat16* op = W1T + (size_t)l * DSUM * HID;
#pragma unroll
    for (int r = 0; r < 32; r += 8)
      op[(size_t)(o0 + ty + r) * DSUM + j0 + tx] = __float2bfloat16(t[tx][ty + r]);
  }
}

// --- GEMM1: 128x128 tile, 4 waves, bias+relu, bf16 out. A staged directly
//     from f32 summary; B via gload_lds from W1T; H via LDS transpose;
//     fused pipelined W2 -> W2T transpose with interleaved nt zero-fill
//     (tiles 0..10 of each 256KB chunk = 176KB; rest done by gemm2). ---
__global__ __launch_bounds__(256) void gemm1_128(
    const float* __restrict__ summary,          // [2048][128] f32
    const __hip_bfloat16* __restrict__ Ball,    // W1T [12][512][128]
    const float* __restrict__ bias,
    __hip_bfloat16* __restrict__ Hall,
    const float* __restrict__ W2,
    __hip_bfloat16* __restrict__ W2T,
    f32x4* __restrict__ zeroBase, int doZero) {
  const int KTOT = DSUM, NTOT = HID;
  __shared__ __hip_bfloat16 shbuf[17408];   // 34816B: staging 2x16KB | H 128x136 | W2 dbuf
  __hip_bfloat16* ldsA = shbuf;
  __hip_bfloat16* ldsB = shbuf + 8192;
  const int l    = blockIdx.z;
  const int n0   = blockIdx.x * 128;
  const int m0   = blockIdx.y * 128;
  const int tid  = threadIdx.x;
  const int wid  = tid >> 6;
  const int lane = tid & 63;
  const int wr = wid >> 1, wc = wid & 1;
  const __hip_bfloat16* Bt = Ball + (size_t)l * NTOT * KTOT;

  f32x4 acc[4][4];
#pragma unroll
  for (int m = 0; m < 4; ++m)
#pragma unroll
    for (int n = 0; n < 4; ++n)
      acc[m][n] = {0.f, 0.f, 0.f, 0.f};

  const int srowi = lane >> 3;
  const int sblk  = (lane & 7) ^ srowi;

  for (int kt = 0; kt < KTOT / 64; ++kt) {
    __syncthreads();
    // B: async gload_lds (pre-swizzled source)
#pragma unroll
    for (int s = 0; s < 4; ++s) {
      int seg = wid * 4 + s;
      int row = seg * 8 + srowi;
      gload_lds16(Bt + (size_t)(n0 + row) * KTOT + kt * 64 + sblk * 8, ldsB + seg * 512);
    }
    // A: reg-staged f32 -> bf16, swizzled ds_write_b64 (summary is L2/L3-hot)
#pragma unroll
    for (int j = 0; j < 8; ++j) {
      int s = j * 256 + tid;
      int r = s >> 4, g = s & 15;
      f32x4 v = *(const f32x4*)(summary + (size_t)(m0 + r) * DSUM + kt * 64 + g * 4);
      s16x4 w;
      w[0] = f2bf(v[0]); w[1] = f2bf(v[1]); w[2] = f2bf(v[2]); w[3] = f2bf(v[3]);
      int ch = g >> 1;
      *(s16x4*)((char*)ldsA + r * 128 + ((ch ^ (r & 7)) << 4) + (g & 1) * 8) = w;
    }
    __syncthreads();
#pragma unroll
    for (int kk = 0; kk < 2; ++kk) {
      short8 af[4], bfr[4];
#pragma unroll
      for (int m = 0; m < 4; ++m) {
        int row = wr * 64 + m * 16 + (lane & 15);
        int off = (kk * 64 + (lane >> 4) * 16) ^ ((row & 7) << 4);
        af[m] = *(const short8*)((const char*)ldsA + row * 128 + off);
      }
#pragma unroll
      for (int n = 0; n < 4; ++n) {
        int row = wc * 64 + n * 16 + (lane & 15);
        int off = (kk * 64 + (lane >> 4) * 16) ^ ((row & 7) << 4);
        bfr[n] = *(const short8*)((const char*)ldsB + row * 128 + off);
      }
#pragma unroll
      for (int m = 0; m < 4; ++m)
#pragma unroll
        for (int n = 0; n < 4; ++n)
          acc[m][n] = __builtin_amdgcn_mfma_f32_16x16x32_bf16(af[m], bfr[n], acc[m][n], 0, 0, 0);
    }
  }

  const int bid = blockIdx.x + 4 * blockIdx.y + 64 * blockIdx.z;   // 0..767

  // H epilogue via LDS: [128][136] bf16 padded tile -> 256B-run stores
  __syncthreads();   // all waves done reading staging LDS
#pragma unroll
  for (int n = 0; n < 4; ++n) {
    int col = wc * 64 + n * 16 + (lane & 15);
    float bb = bias[l * NTOT + n0 + col];
#pragma unroll
    for (int m = 0; m < 4; ++m) {
      int rowb = wr * 64 + m * 16 + ((lane >> 4) << 2);
#pragma unroll
      for (int j = 0; j < 4; ++j) {
        float v = acc[m][n][j] + bb;
        v = v > 0.f ? v : 0.f;
        shbuf[(rowb + j) * 136 + col] = __float2bfloat16(v);
      }
    }
  }
  __syncthreads();
  {
    __hip_bfloat16* H = Hall + (size_t)l * MROWS * HID;
#pragma unroll
    for (int i = 0; i < 8; ++i) {
      int idx = i * 256 + tid;
      int row = idx >> 4, seg = idx & 15;
      short8 v = *(const short8*)(shbuf + row * 136 + seg * 8);
      *(short8*)(H + (size_t)(m0 + row) * HID + n0 + seg * 8) = v;
    }
  }

  // fused W2 -> W2T transpose, pipelined (dbuf LDS, 2-deep reg prefetch,
  // 1 barrier/tile) with interleaved nt zero-fill (tiles 0..10 only).
  {
    float* tb0 = (float*)shbuf;            // 32x33 f32 = 4224B
    float* tb1 = (float*)shbuf + 1056;
    const int tx = tid & 31, ty = tid >> 5;
    const int tbase = bid * 16;
    const f32x4 z = {0.f, 0.f, 0.f, 0.f};
    f32x4* zp = zeroBase + (size_t)bid * 16384;   // 256KB chunk
    float rvA0, rvA1, rvA2, rvA3, rvB0, rvB1, rvB2, rvB3;

#define W2_LOAD(P, tt_) do {                                                \
      int t_ = tbase + (tt_);                                               \
      int lz_ = t_ >> 10, rem_ = t_ & 1023;                                 \
      int j0_ = (rem_ >> 6) * 32, o0_ = (rem_ & 63) * 32;                   \
      const float* ip_ = W2 + (size_t)lz_ * HID * ODIM                      \
                       + (size_t)(j0_ + ty) * ODIM + o0_ + tx;              \
      P##0 = ip_[0];                                                        \
      P##1 = ip_[(size_t)8 * ODIM];                                         \
      P##2 = ip_[(size_t)16 * ODIM];                                        \
      P##3 = ip_[(size_t)24 * ODIM];                                        \
    } while (0)

#define W2_WRITE(buf, P) do {                                               \
      (buf)[(ty +  0) * 33 + tx] = P##0;                                    \
      (buf)[(ty +  8) * 33 + tx] = P##1;                                    \
      (buf)[(ty + 16) * 33 + tx] = P##2;                                    \
      (buf)[(ty + 24) * 33 + tx] = P##3;                                    \
    } while (0)

#define W2_STORE(buf, tt_) do {                                             \
      int t_ = tbase + (tt_);                                               \
      int lz_ = t_ >> 10, rem_ = t_ & 1023;                                 \
      int j0_ = (rem_ >> 6) * 32, o0_ = (rem_ & 63) * 32;                   \
      __hip_bfloat16* op_ = W2T + (size_t)lz_ * HID * ODIM;                 \
      _Pragma("unroll")                                                     \
      for (int r_ = 0; r_ < 4; ++r_)                                        \
        op_[(size_t)(o0_ + ty + 8 * r_) * HID + j0_ + tx] =                 \
            __float2bfloat16((buf)[tx * 33 + ty + 8 * r_]);                 \
    } while (0)

#define ZCHUNK(tt_) do { if (doZero && (tt_) < 11) {                        \
      _Pragma("unroll")                                                     \
      for (int q_ = 0; q_ < 4; ++q_)                                        \
        __builtin_nontemporal_store(z, zp + ((tt_) * 4 + q_) * 256 + tid);  \
    } } while (0)

    W2_LOAD(rvA, 0);
    W2_LOAD(rvB, 1);
    W2_WRITE(tb0, rvA);
    __syncthreads();
#pragma unroll 1
    for (int tt = 0; tt < 16; tt += 2) {
      if (tt + 2 < 16) W2_LOAD(rvA, tt + 2);
      W2_STORE(tb0, tt);
      W2_WRITE(tb1, rvB);
      ZCHUNK(tt);
      __syncthreads();
      if (tt + 3 < 16) W2_LOAD(rvB, tt + 3);
      W2_STORE(tb1, tt + 1);
      if (tt + 2 < 16) W2_WRITE(tb0, rvA);
      ZCHUNK(tt + 1);
      __syncthreads();
    }
#undef W2_LOAD
#undef W2_WRITE
#undef W2_STORE
#undef ZCHUNK
  }
}

// --- GEMM2 (proven pipeline) + zero-fill of bytes [176KB,256KB) of chunk nw
//     (1 nt store/thread at top of iterations t<10; stores are oldest in the
//     vm queue so every counted vmcnt only gets stricter). ---
__global__ __launch_bounds__(512, 1) void gemm2_pipe(
    const __hip_bfloat16* __restrict__ Aall,   // h_bf [12][2048][512]
    const __hip_bfloat16* __restrict__ Ball,   // W2T  [12][2048][512]
    const float* __restrict__ bias,            // b2   [12][2048]
    const float* __restrict__ cs,
    float* __restrict__ O,
    f32x4* __restrict__ zeroBase, int doZero) {
  __shared__ __hip_bfloat16 lds[4 * 16384];    // 128 KiB
  const int orig = blockIdx.x + 8 * blockIdx.y + 64 * blockIdx.z;
  const int nw   = (orig & 7) * 96 + (orig >> 3);
  const int bx   = nw & 7;
  const int by   = (nw >> 3) & 7;
  const int l    = nw >> 6;
  const int n0  = bx * 256;
  const int m0  = by * 256;
  const int tid = threadIdx.x;
  const int wid = tid >> 6, lane = tid & 63;
  const int wm  = wid >> 2, wn = wid & 3;
  const __hip_bfloat16* A  = Aall + (size_t)l * MROWS * HID;
  const __hip_bfloat16* Bt = Ball + (size_t)l * ODIM * HID;
  f32x4* zq = zeroBase + (size_t)nw * 16384 + 11264;   // [176KB, 256KB) of chunk
  const f32x4 zv = {0.f, 0.f, 0.f, 0.f};

  f32x4 acc[8][4];
#pragma unroll
  for (int m = 0; m < 8; ++m)
#pragma unroll
    for (int n = 0; n < 4; ++n)
      acc[m][n] = {0.f, 0.f, 0.f, 0.f};

  const int cidx0 = wid * 128 + lane;
  const int cidx1 = cidx0 + 64;
  const int r0 = cidx0 >> 2, c0 = (cidx0 & 3) ^ ((r0 >> 1) & 3);
  const int r1 = cidx1 >> 2, c1 = (cidx1 & 3) ^ ((r1 >> 1) & 3);

#define STAGE_A(slot, kt) do {                                                      \
    gload_lds16(A + (size_t)(m0 + r0) * HID + (kt) * 32 + c0 * 8,                   \
                lds + (slot) * 16384 + wid * 1024);                                 \
    gload_lds16(A + (size_t)(m0 + r1) * HID + (kt) * 32 + c1 * 8,                   \
                lds + (slot) * 16384 + wid * 1024 + 512);                           \
  } while (0)
#define STAGE_B(slot, kt) do {                                                      \
    gload_lds16(Bt + (size_t)(n0 + r0) * HID + (kt) * 32 + c0 * 8,                  \
                lds + (slot) * 16384 + 8192 + wid * 1024);                          \
    gload_lds16(Bt + (size_t)(n0 + r1) * HID + (kt) * 32 + c1 * 8,                  \
                lds + (slot) * 16384 + 8192 + wid * 1024 + 512);                    \
  } while (0)

  const int kq   = lane >> 4;
  const int rl15 = lane & 15;

#define LD_FRAG(dst, base, rr) do {                                                 \
    int r_ = (rr);                                                                  \
    int off_ = r_ * 64 + ((kq ^ ((r_ >> 1) & 3)) << 4);                             \
    dst = *(const short8*)((const char*)(base) + off_);                             \
  } while (0)

  // prologue: 3 tiles in flight
  STAGE_A(0, 0); STAGE_B(0, 0);
  STAGE_A(1, 1); STAGE_B(1, 1);
  STAGE_A(2, 2); STAGE_B(2, 2);
  asm volatile("s_waitcnt vmcnt(8)" ::: "memory");
  __builtin_amdgcn_s_barrier();

  const int NT = HID / 32;   // 16
  for (int t = 0; t < NT; ++t) {
    const __hip_bfloat16* sa = lds + (t & 3) * 16384;
    const __hip_bfloat16* sb = sa + 8192;
    short8 af[4], bfr[4];

    // zero-fill slice (fire-and-forget; oldest in vm queue this iteration)
    if (doZero && t < 10)
      __builtin_nontemporal_store(zv, zq + t * 512 + tid);

    // ---- phase 0: m-frags 0..3 ----
#pragma unroll
    for (int n = 0; n < 4; ++n) LD_FRAG(bfr[n], sb, wn * 64 + n * 16 + rl15);
#pragma unroll
    for (int mi = 0; mi < 4; ++mi) LD_FRAG(af[mi], sa, wm * 128 + mi * 16 + rl15);
    if (t + 3 < NT) STAGE_A((t + 3) & 3, t + 3);
    __builtin_amdgcn_s_barrier();
    __builtin_amdgcn_s_setprio(1);
#pragma unroll
    for (int mi = 0; mi < 4; ++mi)
#pragma unroll
      for (int n = 0; n < 4; ++n)
        acc[mi][n] = __builtin_amdgcn_mfma_f32_16x16x32_bf16(af[mi], bfr[n], acc[mi][n], 0, 0, 0);
    __builtin_amdgcn_s_setprio(0);
    __builtin_amdgcn_s_barrier();

    // ---- phase 1: m-frags 4..7 (bfr reused) ----
#pragma unroll
    for (int mi = 0; mi < 4; ++mi) LD_FRAG(af[mi], sa, wm * 128 + 64 + mi * 16 + rl15);
    if (t + 3 < NT) STAGE_B((t + 3) & 3, t + 3);
    __builtin_amdgcn_s_barrier();
    __builtin_amdgcn_s_setprio(1);
#pragma unroll
    for (int mi = 0; mi < 4; ++mi)
#pragma unroll
      for (int n = 0; n < 4; ++n)
        acc[4 + mi][n] = __builtin_amdgcn_mfma_f32_16x16x32_bf16(af[mi], bfr[n], acc[4 + mi][n], 0, 0, 0);
    __builtin_amdgcn_s_setprio(0);
    if (t < NT - 1) {
      if (t <= NT - 4)      asm volatile("s_waitcnt vmcnt(8)" ::: "memory");
      else if (t == NT - 3) asm volatile("s_waitcnt vmcnt(4)" ::: "memory");
      else                  asm volatile("s_waitcnt vmcnt(0)" ::: "memory");
    }
    __builtin_amdgcn_s_barrier();
  }
#undef STAGE_A
#undef STAGE_B
#undef LD_FRAG

  // ---- epilogue: bias + RoPE in-reg, per-wave LDS transpose, nt 1KB stores ----
  __syncthreads();
  const int head = bx * 2 + (wn >> 1);
  const int tkv  = wn & 1;
  const int bidx = by * 2 + wm;
  float* slab = O + ((((size_t)(l + L_ACT) * 2 + tkv) * BDIM + bidx) * NHEAD + head) * (PDIM * DHEAD);
  const bool ropeWave = (tkv == 0);

  float bb[4];
#pragma unroll
  for (int n = 0; n < 4; ++n) bb[n] = bias[l * ODIM + n0 + wn * 64 + n * 16 + rl15];

  float* Tw = (float*)lds + wid * 2080;   // 32 x 65 f32 per wave

#pragma unroll
  for (int c = 0; c < 4; ++c) {           // p-chunk [c*32, c*32+32)
#pragma unroll
    for (int mh = 0; mh < 2; ++mh) {
      int mf = c * 2 + mh;
      int pl = mh * 16 + (lane >> 4) * 4;
#pragma unroll
      for (int n = 0; n < 4; ++n) {
#pragma unroll
        for (int j = 0; j < 4; ++j) {
          float v = acc[mf][n][j] + bb[n];
          if (ropeWave && n == 0) {
            float partner = __shfl_xor(v, 8);
            int p = c * 32 + pl + j;
            float cv = cs[p * 8 + (lane & 7)];
            float sv = cs[1024 + p * 8 + (lane & 7)];
            v = v * cv + (((lane & 15) < 8) ? -partner : partner) * sv;
          }
          Tw[(pl + j) * 65 + n * 16 + rl15] = v;
        }
      }
    }
#pragma unroll
    for (int it = 0; it < 8; ++it) {
      int pl = it * 4 + (lane >> 4);
      f32x4 vv = *(const f32x4*)(Tw + pl * 65 + rl15 * 4);
      __builtin_nontemporal_store(vv, (f32x4*)(slab + (size_t)(c * 32 + pl) * DHEAD + rl15 * 4));
    }
  }
}

extern "C" void kernel_launch(void* const* d_in, const int* in_sizes, int n_in,
                              void* d_out, int out_size, void* d_ws, size_t ws_size,
                              hipStream_t stream) {
  const float* summary   = (const float*)d_in[0];
  const int*   positions = (const int*)d_in[1];
  const float* W1 = (const float*)d_in[2];
  const float* b1 = (const float*)d_in[3];
  const float* W2 = (const float*)d_in[4];
  const float* b2 = (const float*)d_in[5];
  float* out = (float*)d_out;

  // Scratch: h_bf 25165824 | W2T 25165824 | W1T 1572864 | cs 8192
  const size_t SCRATCH_BYTES = 25165824ULL + 25165824ULL + 1572864ULL + 8192ULL;
  const bool useWs = (ws_size >= SCRATCH_BYTES);
  char* sc = useWs ? (char*)d_ws : (char*)d_out;
  __hip_bfloat16* h_bf = (__hip_bfloat16*)sc;
  __hip_bfloat16* W2T  = (__hip_bfloat16*)(sc + 25165824);
  __hip_bfloat16* W1T  = (__hip_bfloat16*)(sc + 50331648);
  float*          cs   = (float*)(sc + 51904512);

  prep_tiny<<<769, 256, 0, stream>>>(positions, W1, cs, W1T);

  gemm1_128<<<dim3(HID / 128, MROWS / 128, L_ACT), 256, 0, stream>>>(
      summary, W1T, b1, h_bf, W2, W2T, (f32x4*)d_out, useWs ? 1 : 0);
  gemm2_pipe<<<dim3(ODIM / 256, MROWS / 256, L_ACT), 512, 0, stream>>>(
      h_bf, W2T, b2, cs, out, (f32x4*)d_out, useWs ? 1 : 0);

  if (!useWs)   // scratch aliased d_out: zero AFTER gemm2 has consumed it
    zerofill_kernel<<<2048, 256, 0, stream>>>((f32x4*)d_out, 12582912);
}

// Round 12
// 126.695 us; speedup vs baseline: 1.1557x; 1.0086x over previous
//
#include <hip/hip_runtime.h>
#include <hip/hip_bf16.h>

// Problem constants
#define L_ACT   12
#define BDIM    16
#define PDIM    128
#define DSUM    128
#define HID     512
#define ODIM    2048
#define NHEAD   16
#define DHEAD   64
#define MROWS   2048   // B*P rows per layer

typedef short s16x4  __attribute__((ext_vector_type(4)));
typedef short short8 __attribute__((ext_vector_type(8)));
typedef float f32x4  __attribute__((ext_vector_type(4)));

__device__ __forceinline__ void gload_lds16(const __hip_bfloat16* g, __hip_bfloat16* l) {
  __builtin_amdgcn_global_load_lds(
      (const __attribute__((address_space(1))) unsigned int*)g,
      (__attribute__((address_space(3))) unsigned int*)l, 16, 0, 0);
}

__device__ __forceinline__ short f2bf(float x) {
  __hip_bfloat16 h = __float2bfloat16(x);
  return *reinterpret_cast<short*>(&h);
}

// --- zero-fill (fallback path only) ---
__global__ __launch_bounds__(256) void zerofill_kernel(f32x4* __restrict__ p, int n16) {
  int stride = gridDim.x * 256;
  for (int i = blockIdx.x * 256 + threadIdx.x; i < n16; i += stride)
    p[i] = {0.f, 0.f, 0.f, 0.f};
}

// --- prep_tiny: blocks 0..767 -> W1T transpose; block 768 -> cos/sin table ---
__global__ __launch_bounds__(256) void prep_tiny(
    const int* __restrict__ positions, const float* __restrict__ W1,
    float* __restrict__ cs, __hip_bfloat16* __restrict__ W1T) {
  const int bid = blockIdx.x;
  const int tid = threadIdx.x;
  if (bid == 768) {
#pragma unroll
    for (int q = 0; q < 4; ++q) {
      int i = q * 256 + tid;
      int p = i >> 3, f = i & 7;
      double inv = pow(10000.0, -(double)f / 8.0);
      double ang = (double)positions[p] * inv;
      cs[i]        = (float)cos(ang);
      cs[1024 + i] = (float)sin(ang);
    }
  } else {
    __shared__ float t[32][33];
    int bx = bid & 15, by = (bid >> 4) & 3, l = bid >> 6;   // 16 o-tiles x 4 j-tiles
    int o0 = bx * 32, j0 = by * 32;
    int tx = tid & 31, ty = tid >> 5;   // 32x8
    const float* ip = W1 + (size_t)l * DSUM * HID;
#pragma unroll
    for (int r = 0; r < 32; r += 8)
      t[ty + r][tx] = ip[(size_t)(j0 + ty + r) * HID + o0 + tx];
    __syncthreads();
    __hip_bfloat16* op = W1T + (size_t)l * DSUM * HID;
#pragma unroll
    for (int r = 0; r < 32; r += 8)
      op[(size_t)(o0 + ty + r) * DSUM + j0 + tx] = __float2bfloat16(t[tx][ty + r]);
  }
}

// --- GEMM1: 128x128 tile, 4 waves, bias+relu, bf16 out. A staged directly
//     from f32 summary; B via gload_lds from W1T; H via LDS transpose;
//     fused pipelined W2 -> W2T transpose with interleaved nt zero-fill
//     (tiles 0..7 = 128KB of this block's chunk in [96MB,201.3MB)). ---
__global__ __launch_bounds__(256) void gemm1_128(
    const float* __restrict__ summary,          // [2048][128] f32
    const __hip_bfloat16* __restrict__ Ball,    // W1T [12][512][128]
    const float* __restrict__ bias,
    __hip_bfloat16* __restrict__ Hall,
    const float* __restrict__ W2,
    __hip_bfloat16* __restrict__ W2T,
    f32x4* __restrict__ zeroBase, int doZero) {
  const int KTOT = DSUM, NTOT = HID;
  __shared__ __hip_bfloat16 shbuf[17408];   // 34816B: staging 2x16KB | H 128x136 | W2 dbuf
  __hip_bfloat16* ldsA = shbuf;
  __hip_bfloat16* ldsB = shbuf + 8192;
  const int l    = blockIdx.z;
  const int n0   = blockIdx.x * 128;
  const int m0   = blockIdx.y * 128;
  const int tid  = threadIdx.x;
  const int wid  = tid >> 6;
  const int lane = tid & 63;
  const int wr = wid >> 1, wc = wid & 1;
  const __hip_bfloat16* Bt = Ball + (size_t)l * NTOT * KTOT;

  f32x4 acc[4][4];
#pragma unroll
  for (int m = 0; m < 4; ++m)
#pragma unroll
    for (int n = 0; n < 4; ++n)
      acc[m][n] = {0.f, 0.f, 0.f, 0.f};

  const int srowi = lane >> 3;
  const int sblk  = (lane & 7) ^ srowi;

  for (int kt = 0; kt < KTOT / 64; ++kt) {
    __syncthreads();
    // B: async gload_lds (pre-swizzled source)
#pragma unroll
    for (int s = 0; s < 4; ++s) {
      int seg = wid * 4 + s;
      int row = seg * 8 + srowi;
      gload_lds16(Bt + (size_t)(n0 + row) * KTOT + kt * 64 + sblk * 8, ldsB + seg * 512);
    }
    // A: reg-staged f32 -> bf16, swizzled ds_write_b64 (summary is L2/L3-hot)
#pragma unroll
    for (int j = 0; j < 8; ++j) {
      int s = j * 256 + tid;
      int r = s >> 4, g = s & 15;
      f32x4 v = *(const f32x4*)(summary + (size_t)(m0 + r) * DSUM + kt * 64 + g * 4);
      s16x4 w;
      w[0] = f2bf(v[0]); w[1] = f2bf(v[1]); w[2] = f2bf(v[2]); w[3] = f2bf(v[3]);
      int ch = g >> 1;
      *(s16x4*)((char*)ldsA + r * 128 + ((ch ^ (r & 7)) << 4) + (g & 1) * 8) = w;
    }
    __syncthreads();
#pragma unroll
    for (int kk = 0; kk < 2; ++kk) {
      short8 af[4], bfr[4];
#pragma unroll
      for (int m = 0; m < 4; ++m) {
        int row = wr * 64 + m * 16 + (lane & 15);
        int off = (kk * 64 + (lane >> 4) * 16) ^ ((row & 7) << 4);
        af[m] = *(const short8*)((const char*)ldsA + row * 128 + off);
      }
#pragma unroll
      for (int n = 0; n < 4; ++n) {
        int row = wc * 64 + n * 16 + (lane & 15);
        int off = (kk * 64 + (lane >> 4) * 16) ^ ((row & 7) << 4);
        bfr[n] = *(const short8*)((const char*)ldsB + row * 128 + off);
      }
#pragma unroll
      for (int m = 0; m < 4; ++m)
#pragma unroll
        for (int n = 0; n < 4; ++n)
          acc[m][n] = __builtin_amdgcn_mfma_f32_16x16x32_bf16(af[m], bfr[n], acc[m][n], 0, 0, 0);
    }
  }

  const int bid = blockIdx.x + 4 * blockIdx.y + 64 * blockIdx.z;   // 0..767

  // H epilogue via LDS: [128][136] bf16 padded tile -> 256B-run stores
  __syncthreads();   // all waves done reading staging LDS
#pragma unroll
  for (int n = 0; n < 4; ++n) {
    int col = wc * 64 + n * 16 + (lane & 15);
    float bb = bias[l * NTOT + n0 + col];
#pragma unroll
    for (int m = 0; m < 4; ++m) {
      int rowb = wr * 64 + m * 16 + ((lane >> 4) << 2);
#pragma unroll
      for (int j = 0; j < 4; ++j) {
        float v = acc[m][n][j] + bb;
        v = v > 0.f ? v : 0.f;
        shbuf[(rowb + j) * 136 + col] = __float2bfloat16(v);
      }
    }
  }
  __syncthreads();
  {
    __hip_bfloat16* H = Hall + (size_t)l * MROWS * HID;
#pragma unroll
    for (int i = 0; i < 8; ++i) {
      int idx = i * 256 + tid;
      int row = idx >> 4, seg = idx & 15;
      short8 v = *(const short8*)(shbuf + row * 136 + seg * 8);
      *(short8*)(H + (size_t)(m0 + row) * HID + n0 + seg * 8) = v;
    }
  }

  // fused W2 -> W2T transpose, pipelined (dbuf LDS, 2-deep reg prefetch,
  // 1 barrier/tile) with interleaved nt zero-fill (tiles 0..7 = 128KB).
  {
    float* tb0 = (float*)shbuf;            // 32x33 f32 = 4224B
    float* tb1 = (float*)shbuf + 1056;
    const int tx = tid & 31, ty = tid >> 5;
    const int tbase = bid * 16;
    const f32x4 z = {0.f, 0.f, 0.f, 0.f};
    f32x4* zp = zeroBase + (size_t)bid * 8192;   // 128KB chunk
    float rvA0, rvA1, rvA2, rvA3, rvB0, rvB1, rvB2, rvB3;

#define W2_LOAD(P, tt_) do {                                                \
      int t_ = tbase + (tt_);                                               \
      int lz_ = t_ >> 10, rem_ = t_ & 1023;                                 \
      int j0_ = (rem_ >> 6) * 32, o0_ = (rem_ & 63) * 32;                   \
      const float* ip_ = W2 + (size_t)lz_ * HID * ODIM                      \
                       + (size_t)(j0_ + ty) * ODIM + o0_ + tx;              \
      P##0 = ip_[0];                                                        \
      P##1 = ip_[(size_t)8 * ODIM];                                         \
      P##2 = ip_[(size_t)16 * ODIM];                                        \
      P##3 = ip_[(size_t)24 * ODIM];                                        \
    } while (0)

#define W2_WRITE(buf, P) do {                                               \
      (buf)[(ty +  0) * 33 + tx] = P##0;                                    \
      (buf)[(ty +  8) * 33 + tx] = P##1;                                    \
      (buf)[(ty + 16) * 33 + tx] = P##2;                                    \
      (buf)[(ty + 24) * 33 + tx] = P##3;                                    \
    } while (0)

#define W2_STORE(buf, tt_) do {                                             \
      int t_ = tbase + (tt_);                                               \
      int lz_ = t_ >> 10, rem_ = t_ & 1023;                                 \
      int j0_ = (rem_ >> 6) * 32, o0_ = (rem_ & 63) * 32;                   \
      __hip_bfloat16* op_ = W2T + (size_t)lz_ * HID * ODIM;                 \
      _Pragma("unroll")                                                     \
      for (int r_ = 0; r_ < 4; ++r_)                                        \
        op_[(size_t)(o0_ + ty + 8 * r_) * HID + j0_ + tx] =                 \
            __float2bfloat16((buf)[tx * 33 + ty + 8 * r_]);                 \
    } while (0)

#define ZCHUNK(tt_) do { if (doZero && (tt_) < 8) {                         \
      _Pragma("unroll")                                                     \
      for (int q_ = 0; q_ < 4; ++q_)                                        \
        __builtin_nontemporal_store(z, zp + ((tt_) * 4 + q_) * 256 + tid);  \
    } } while (0)

    W2_LOAD(rvA, 0);
    W2_LOAD(rvB, 1);
    W2_WRITE(tb0, rvA);
    __syncthreads();
#pragma unroll 1
    for (int tt = 0; tt < 16; tt += 2) {
      if (tt + 2 < 16) W2_LOAD(rvA, tt + 2);
      W2_STORE(tb0, tt);
      W2_WRITE(tb1, rvB);
      ZCHUNK(tt);
      __syncthreads();
      if (tt + 3 < 16) W2_LOAD(rvB, tt + 3);
      W2_STORE(tb1, tt + 1);
      if (tt + 2 < 16) W2_WRITE(tb0, rvA);
      ZCHUNK(tt + 1);
      __syncthreads();
    }
#undef W2_LOAD
#undef W2_WRITE
#undef W2_STORE
#undef ZCHUNK
  }
}

// --- GEMM2: 256m x 128n tile, 256 threads (4 waves, 2Mx2N), BK=32,
//     3-slot LDS ring (72KB -> 2 blocks/CU), depth-2 prefetch with counted
//     vmcnt, 16x16x32 MFMA, XCD-chunked swizzle (1536 blocks), per-t nt
//     zero slice (64KB/block), LDS-transpose epilogue, nt 1KB slab stores.
//     Per-wave inner loop identical to the proven 256x256 kernel. ---
__global__ __launch_bounds__(256, 2) void gemm2_pipe(
    const __hip_bfloat16* __restrict__ Aall,   // h_bf [12][2048][512]
    const __hip_bfloat16* __restrict__ Ball,   // W2T  [12][2048][512]
    const float* __restrict__ bias,            // b2   [12][2048]
    const float* __restrict__ cs,
    float* __restrict__ O,
    f32x4* __restrict__ zeroBase, int doZero) {
  __shared__ __hip_bfloat16 lds[3 * 12288];    // 3 slots x (A 16KB + B 8KB) = 72 KiB
  const int orig = blockIdx.x + 16 * blockIdx.y + 128 * blockIdx.z;   // x fastest
  const int nw   = (orig & 7) * 192 + (orig >> 3);   // bijective, 1536 % 8 == 0
  const int bx   = nw & 15;
  const int by   = (nw >> 4) & 7;
  const int l    = nw >> 7;
  const int n0  = bx * 128;
  const int m0  = by * 256;
  const int tid = threadIdx.x;
  const int wid = tid >> 6, lane = tid & 63;
  const int wm  = wid >> 1, wn = wid & 1;
  const __hip_bfloat16* A  = Aall + (size_t)l * MROWS * HID;
  const __hip_bfloat16* Bt = Ball + (size_t)l * ODIM * HID;
  f32x4* zq = zeroBase + (size_t)nw * 4096;    // 64KB slice of [0, 96MB)
  const f32x4 zv = {0.f, 0.f, 0.f, 0.f};

  f32x4 acc[8][4];
#pragma unroll
  for (int m = 0; m < 8; ++m)
#pragma unroll
    for (int n = 0; n < 4; ++n)
      acc[m][n] = {0.f, 0.f, 0.f, 0.f};

  // staging chunks: A = 1024 x 16B (4/thread), B = 512 x 16B (2/thread);
  // linear LDS dest, inverse chunk swizzle on the global source.
  int ra[4], ca[4], rb[2], cb[2];
#pragma unroll
  for (int j = 0; j < 4; ++j) {
    int cx = j * 256 + tid;
    ra[j] = cx >> 2; ca[j] = (cx & 3) ^ ((ra[j] >> 1) & 3);
  }
#pragma unroll
  for (int j = 0; j < 2; ++j) {
    int cx = j * 256 + tid;
    rb[j] = cx >> 2; cb[j] = (cx & 3) ^ ((rb[j] >> 1) & 3);
  }

#define STAGE_A(slot, kt) do {                                                      \
    _Pragma("unroll")                                                               \
    for (int j_ = 0; j_ < 4; ++j_)                                                  \
      gload_lds16(A + (size_t)(m0 + ra[j_]) * HID + (kt) * 32 + ca[j_] * 8,         \
                  lds + (slot) * 12288 + j_ * 2048 + wid * 512);                    \
  } while (0)
#define STAGE_B(slot, kt) do {                                                      \
    _Pragma("unroll")                                                               \
    for (int j_ = 0; j_ < 2; ++j_)                                                  \
      gload_lds16(Bt + (size_t)(n0 + rb[j_]) * HID + (kt) * 32 + cb[j_] * 8,        \
                  lds + (slot) * 12288 + 8192 + j_ * 2048 + wid * 512);             \
  } while (0)

  const int kq   = lane >> 4;
  const int rl15 = lane & 15;

#define LD_FRAG(dst, base, rr) do {                                                 \
    int r_ = (rr);                                                                  \
    int off_ = r_ * 64 + ((kq ^ ((r_ >> 1) & 3)) << 4);                             \
    dst = *(const short8*)((const char*)(base) + off_);                             \
  } while (0)

  // prologue: 2 tiles in flight (12 loads/thread... 6 per tile)
  STAGE_A(0, 0); STAGE_B(0, 0);
  STAGE_A(1, 1); STAGE_B(1, 1);
  asm volatile("s_waitcnt vmcnt(6)" ::: "memory");   // tile 0 landed
  __builtin_amdgcn_s_barrier();

  const int NT = HID / 32;   // 16
  for (int t = 0; t < NT; ++t) {
    const int cur = t % 3;
    const __hip_bfloat16* sa = lds + cur * 12288;
    const __hip_bfloat16* sb = sa + 8192;
    short8 af[4], bfr[4];

    // zero-fill slice (fire-and-forget; only makes counted waits stricter)
    if (doZero)
      __builtin_nontemporal_store(zv, zq + t * 256 + tid);

    // ---- phase 0: m-frags 0..3 ----
#pragma unroll
    for (int n = 0; n < 4; ++n) LD_FRAG(bfr[n], sb, wn * 64 + n * 16 + rl15);
#pragma unroll
    for (int mi = 0; mi < 4; ++mi) LD_FRAG(af[mi], sa, wm * 128 + mi * 16 + rl15);
    if (t + 2 < NT) STAGE_A((t + 2) % 3, t + 2);
    __builtin_amdgcn_s_barrier();
    __builtin_amdgcn_s_setprio(1);
#pragma unroll
    for (int mi = 0; mi < 4; ++mi)
#pragma unroll
      for (int n = 0; n < 4; ++n)
        acc[mi][n] = __builtin_amdgcn_mfma_f32_16x16x32_bf16(af[mi], bfr[n], acc[mi][n], 0, 0, 0);
    __builtin_amdgcn_s_setprio(0);
    __builtin_amdgcn_s_barrier();

    // ---- phase 1: m-frags 4..7 (bfr reused) ----
#pragma unroll
    for (int mi = 0; mi < 4; ++mi) LD_FRAG(af[mi], sa, wm * 128 + 64 + mi * 16 + rl15);
    if (t + 2 < NT) STAGE_B((t + 2) % 3, t + 2);
    __builtin_amdgcn_s_barrier();
    __builtin_amdgcn_s_setprio(1);
#pragma unroll
    for (int mi = 0; mi < 4; ++mi)
#pragma unroll
      for (int n = 0; n < 4; ++n)
        acc[4 + mi][n] = __builtin_amdgcn_mfma_f32_16x16x32_bf16(af[mi], bfr[n], acc[4 + mi][n], 0, 0, 0);
    __builtin_amdgcn_s_setprio(0);
    if (t < NT - 2)       asm volatile("s_waitcnt vmcnt(6)" ::: "memory");
    else if (t == NT - 2) asm volatile("s_waitcnt vmcnt(0)" ::: "memory");
    __builtin_amdgcn_s_barrier();
  }
#undef STAGE_A
#undef STAGE_B
#undef LD_FRAG

  // ---- epilogue: bias + RoPE in-reg, per-wave LDS transpose, nt 1KB stores ----
  __syncthreads();
  const int head = bx;                 // (n0 + wn*64) >> 7 == bx
  const int tkv  = wn;                 // ((n0 + wn*64) >> 6) & 1 == wn
  const int bidx = by * 2 + wm;
  float* slab = O + ((((size_t)(l + L_ACT) * 2 + tkv) * BDIM + bidx) * NHEAD + head) * (PDIM * DHEAD);
  const bool ropeWave = (tkv == 0);

  float bb[4];
#pragma unroll
  for (int n = 0; n < 4; ++n) bb[n] = bias[l * ODIM + n0 + wn * 64 + n * 16 + rl15];

  float* Tw = (float*)lds + wid * 2080;   // 32 x 65 f32 per wave (4 waves = 33KB)

#pragma unroll
  for (int c = 0; c < 4; ++c) {           // p-chunk [c*32, c*32+32)
#pragma unroll
    for (int mh = 0; mh < 2; ++mh) {
      int mf = c * 2 + mh;
      int pl = mh * 16 + (lane >> 4) * 4;
#pragma unroll
      for (int n = 0; n < 4; ++n) {
#pragma unroll
        for (int j = 0; j < 4; ++j) {
          float v = acc[mf][n][j] + bb[n];
          if (ropeWave && n == 0) {
            float partner = __shfl_xor(v, 8);
            int p = c * 32 + pl + j;
            float cv = cs[p * 8 + (lane & 7)];
            float sv = cs[1024 + p * 8 + (lane & 7)];
            v = v * cv + (((lane & 15) < 8) ? -partner : partner) * sv;
          }
          Tw[(pl + j) * 65 + n * 16 + rl15] = v;
        }
      }
    }
#pragma unroll
    for (int it = 0; it < 8; ++it) {
      int pl = it * 4 + (lane >> 4);
      f32x4 vv = *(const f32x4*)(Tw + pl * 65 + rl15 * 4);
      __builtin_nontemporal_store(vv, (f32x4*)(slab + (size_t)(c * 32 + pl) * DHEAD + rl15 * 4));
    }
  }
}

extern "C" void kernel_launch(void* const* d_in, const int* in_sizes, int n_in,
                              void* d_out, int out_size, void* d_ws, size_t ws_size,
                              hipStream_t stream) {
  const float* summary   = (const float*)d_in[0];
  const int*   positions = (const int*)d_in[1];
  const float* W1 = (const float*)d_in[2];
  const float* b1 = (const float*)d_in[3];
  const float* W2 = (const float*)d_in[4];
  const float* b2 = (const float*)d_in[5];
  float* out = (float*)d_out;

  // Scratch: h_bf 25165824 | W2T 25165824 | W1T 1572864 | cs 8192
  const size_t SCRATCH_BYTES = 25165824ULL + 25165824ULL + 1572864ULL + 8192ULL;
  const bool useWs = (ws_size >= SCRATCH_BYTES);
  char* sc = useWs ? (char*)d_ws : (char*)d_out;
  __hip_bfloat16* h_bf = (__hip_bfloat16*)sc;
  __hip_bfloat16* W2T  = (__hip_bfloat16*)(sc + 25165824);
  __hip_bfloat16* W1T  = (__hip_bfloat16*)(sc + 50331648);
  float*          cs   = (float*)(sc + 51904512);

  prep_tiny<<<769, 256, 0, stream>>>(positions, W1, cs, W1T);

  // zero region split: gemm2 covers [0, 100663296), gemm1 covers the rest.
  gemm1_128<<<dim3(HID / 128, MROWS / 128, L_ACT), 256, 0, stream>>>(
      summary, W1T, b1, h_bf, W2, W2T,
      (f32x4*)((char*)d_out + 100663296), useWs ? 1 : 0);
  gemm2_pipe<<<dim3(ODIM / 128, MROWS / 256, L_ACT), 256, 0, stream>>>(
      h_bf, W2T, b2, cs, out, (f32x4*)d_out, useWs ? 1 : 0);

  if (!useWs)   // scratch aliased d_out: zero AFTER gemm2 has consumed it
    zerofill_kernel<<<2048, 256, 0, stream>>>((f32x4*)d_out, 12582912);
}

// Round 14
// 124.437 us; speedup vs baseline: 1.1767x; 1.0181x over previous
//
#include <hip/hip_runtime.h>
#include <hip/hip_bf16.h>

// Problem constants
#define L_ACT   12
#define BDIM    16
#define PDIM    128
#define DSUM    128
#define HID     512
#define ODIM    2048
#define NHEAD   16
#define DHEAD   64
#define MROWS   2048   // B*P rows per layer

typedef short s16x4  __attribute__((ext_vector_type(4)));
typedef short short8 __attribute__((ext_vector_type(8)));
typedef float f32x4  __attribute__((ext_vector_type(4)));

__device__ __forceinline__ void gload_lds16(const __hip_bfloat16* g, __hip_bfloat16* l) {
  __builtin_amdgcn_global_load_lds(
      (const __attribute__((address_space(1))) unsigned int*)g,
      (__attribute__((address_space(3))) unsigned int*)l, 16, 0, 0);
}

__device__ __forceinline__ short f2bf(float x) {
  __hip_bfloat16 h = __float2bfloat16(x);
  return *reinterpret_cast<short*>(&h);
}

// --- zero-fill (fallback path only) ---
__global__ __launch_bounds__(256) void zerofill_kernel(f32x4* __restrict__ p, int n16) {
  int stride = gridDim.x * 256;
  for (int i = blockIdx.x * 256 + threadIdx.x; i < n16; i += stride)
    p[i] = {0.f, 0.f, 0.f, 0.f};
}

// --- GEMM1: 128x128 tile, 4 waves, bias+relu, bf16 out.
//     A staged per-kt from f32 summary (reg cvt + swizzled ds_write).
//     B staged ONCE per block directly from f32 W1 (coalesced j-major loads,
//     cvt, ds_write_b64 into persistent full-K swizzled tile) - no W1T, no
//     prep kernel. Block 0 additionally computes the cos/sin table.
//     H via LDS transpose; fused pipelined W2 -> W2T transpose with
//     interleaved nt zero-fill (tiles 0..7 = 128KB of chunk).
//     LDS: B2 32KB [0,16384e) + A 16KB [16384e,24576e) = 48KB.  (R13 bug:
//     A tile is 8192 elements, shbuf[20480] overflowed by 8KB -> fixed.) ---
__global__ __launch_bounds__(256) void gemm1_128(
    const float* __restrict__ summary,          // [2048][128] f32
    const float* __restrict__ W1,               // [12][128][512] f32
    const int*   __restrict__ positions,
    const float* __restrict__ bias,
    __hip_bfloat16* __restrict__ Hall,
    const float* __restrict__ W2,
    __hip_bfloat16* __restrict__ W2T,
    float* __restrict__ cs,
    f32x4* __restrict__ zeroBase, int doZero) {
  const int KTOT = DSUM, NTOT = HID;
  __shared__ __hip_bfloat16 shbuf[24576];   // 49152B: B2 32KB | A 16KB (H tile reuses)
  __hip_bfloat16* ldsB2 = shbuf;            // [128 r][256B] full-K swizzled B tile
  __hip_bfloat16* ldsA  = shbuf + 16384;    // per-kt A tile [128 r][128B] = 8192 elems
  const int l    = blockIdx.z;
  const int n0   = blockIdx.x * 128;
  const int m0   = blockIdx.y * 128;
  const int tid  = threadIdx.x;
  const int wid  = tid >> 6;
  const int lane = tid & 63;
  const int wr = wid >> 1, wc = wid & 1;
  const int bid = blockIdx.x + 4 * blockIdx.y + 64 * blockIdx.z;   // 0..767

  // block 0: cos/sin table (consumed by gemm2; stream order guarantees visibility)
  if (bid == 0) {
#pragma unroll
    for (int q = 0; q < 4; ++q) {
      int i = q * 256 + tid;
      int p = i >> 3, f = i & 7;
      double inv = pow(10000.0, -(double)f / 8.0);
      double ang = (double)positions[p] * inv;
      cs[i]        = (float)cos(ang);
      cs[1024 + i] = (float)sin(ang);
    }
  }

  // B2 staging: W1[l][j][n0+r] -> ldsB2[r][(j>>3)^(r&7)][j&7]
  {
    const float* Wp = W1 + (size_t)l * DSUM * HID + n0;
#pragma unroll
    for (int q = 0; q < 16; ++q) {
      int g  = q * 256 + tid;
      int j4 = g >> 7;            // 0..31 (4 consecutive j)
      int r  = g & 127;
      s16x4 w;
#pragma unroll
      for (int jj = 0; jj < 4; ++jj)
        w[jj] = f2bf(Wp[(size_t)(j4 * 4 + jj) * HID + r]);
      int chunk = (j4 >> 1) ^ (r & 7);
      *(s16x4*)((char*)ldsB2 + r * 256 + chunk * 16 + (j4 & 1) * 8) = w;
    }
  }

  f32x4 acc[4][4];
#pragma unroll
  for (int m = 0; m < 4; ++m)
#pragma unroll
    for (int n = 0; n < 4; ++n)
      acc[m][n] = {0.f, 0.f, 0.f, 0.f};

  const int kq = lane >> 4;

  for (int kt = 0; kt < KTOT / 64; ++kt) {
    __syncthreads();   // kt=0: orders B2 writes before reads; also guards ldsA reuse
    // A: reg-staged f32 -> bf16, swizzled ds_write_b64 (summary is L2/L3-hot)
#pragma unroll
    for (int j = 0; j < 8; ++j) {
      int s = j * 256 + tid;
      int r = s >> 4, g = s & 15;
      f32x4 v = *(const f32x4*)(summary + (size_t)(m0 + r) * DSUM + kt * 64 + g * 4);
      s16x4 w;
      w[0] = f2bf(v[0]); w[1] = f2bf(v[1]); w[2] = f2bf(v[2]); w[3] = f2bf(v[3]);
      int ch = g >> 1;
      *(s16x4*)((char*)ldsA + r * 128 + ((ch ^ (r & 7)) << 4) + (g & 1) * 8) = w;
    }
    __syncthreads();
#pragma unroll
    for (int kk = 0; kk < 2; ++kk) {
      short8 af[4], bfr[4];
#pragma unroll
      for (int m = 0; m < 4; ++m) {
        int row = wr * 64 + m * 16 + (lane & 15);
        int off = (kk * 64 + kq * 16) ^ ((row & 7) << 4);
        af[m] = *(const short8*)((const char*)ldsA + row * 128 + off);
      }
#pragma unroll
      for (int n = 0; n < 4; ++n) {
        int row = wc * 64 + n * 16 + (lane & 15);
        int chunk = (kt * 8 + kk * 4 + kq) ^ (row & 7);
        bfr[n] = *(const short8*)((const char*)ldsB2 + row * 256 + chunk * 16);
      }
#pragma unroll
      for (int m = 0; m < 4; ++m)
#pragma unroll
        for (int n = 0; n < 4; ++n)
          acc[m][n] = __builtin_amdgcn_mfma_f32_16x16x32_bf16(af[m], bfr[n], acc[m][n], 0, 0, 0);
    }
  }

  // H epilogue via LDS: [128][136] bf16 padded tile -> 256B-run stores
  __syncthreads();   // all waves done reading B2/A staging
#pragma unroll
  for (int n = 0; n < 4; ++n) {
    int col = wc * 64 + n * 16 + (lane & 15);
    float bb = bias[l * NTOT + n0 + col];
#pragma unroll
    for (int m = 0; m < 4; ++m) {
      int rowb = wr * 64 + m * 16 + ((lane >> 4) << 2);
#pragma unroll
      for (int j = 0; j < 4; ++j) {
        float v = acc[m][n][j] + bb;
        v = v > 0.f ? v : 0.f;
        shbuf[(rowb + j) * 136 + col] = __float2bfloat16(v);
      }
    }
  }
  __syncthreads();
  {
    __hip_bfloat16* H = Hall + (size_t)l * MROWS * HID;
#pragma unroll
    for (int i = 0; i < 8; ++i) {
      int idx = i * 256 + tid;
      int row = idx >> 4, seg = idx & 15;
      short8 v = *(const short8*)(shbuf + row * 136 + seg * 8);
      *(short8*)(H + (size_t)(m0 + row) * HID + n0 + seg * 8) = v;
    }
  }
  __syncthreads();   // H reads done before W2 section overwrites shbuf

  // fused W2 -> W2T transpose, pipelined (dbuf LDS, 2-deep reg prefetch,
  // 1 barrier/tile) with interleaved nt zero-fill (tiles 0..7 = 128KB).
  {
    float* tb0 = (float*)shbuf;            // 32x33 f32 = 4224B
    float* tb1 = (float*)shbuf + 1056;
    const int tx = tid & 31, ty = tid >> 5;
    const int tbase = bid * 16;
    const f32x4 z = {0.f, 0.f, 0.f, 0.f};
    f32x4* zp = zeroBase + (size_t)bid * 8192;   // 128KB chunk
    float rvA0, rvA1, rvA2, rvA3, rvB0, rvB1, rvB2, rvB3;

#define W2_LOAD(P, tt_) do {                                                \
      int t_ = tbase + (tt_);                                               \
      int lz_ = t_ >> 10, rem_ = t_ & 1023;                                 \
      int j0_ = (rem_ >> 6) * 32, o0_ = (rem_ & 63) * 32;                   \
      const float* ip_ = W2 + (size_t)lz_ * HID * ODIM                      \
                       + (size_t)(j0_ + ty) * ODIM + o0_ + tx;              \
      P##0 = ip_[0];                                                        \
      P##1 = ip_[(size_t)8 * ODIM];                                         \
      P##2 = ip_[(size_t)16 * ODIM];                                        \
      P##3 = ip_[(size_t)24 * ODIM];                                        \
    } while (0)

#define W2_WRITE(buf, P) do {                                               \
      (buf)[(ty +  0) * 33 + tx] = P##0;                                    \
      (buf)[(ty +  8) * 33 + tx] = P##1;                                    \
      (buf)[(ty + 16) * 33 + tx] = P##2;                                    \
      (buf)[(ty + 24) * 33 + tx] = P##3;                                    \
    } while (0)

#define W2_STORE(buf, tt_) do {                                             \
      int t_ = tbase + (tt_);                                               \
      int lz_ = t_ >> 10, rem_ = t_ & 1023;                                 \
      int j0_ = (rem_ >> 6) * 32, o0_ = (rem_ & 63) * 32;                   \
      __hip_bfloat16* op_ = W2T + (size_t)lz_ * HID * ODIM;                 \
      _Pragma("unroll")                                                     \
      for (int r_ = 0; r_ < 4; ++r_)                                        \
        op_[(size_t)(o0_ + ty + 8 * r_) * HID + j0_ + tx] =                 \
            __float2bfloat16((buf)[tx * 33 + ty + 8 * r_]);                 \
    } while (0)

#define ZCHUNK(tt_) do { if (doZero && (tt_) < 8) {                         \
      _Pragma("unroll")                                                     \
      for (int q_ = 0; q_ < 4; ++q_)                                        \
        __builtin_nontemporal_store(z, zp + ((tt_) * 4 + q_) * 256 + tid);  \
    } } while (0)

    W2_LOAD(rvA, 0);
    W2_LOAD(rvB, 1);
    W2_WRITE(tb0, rvA);
    __syncthreads();
#pragma unroll 1
    for (int tt = 0; tt < 16; tt += 2) {
      if (tt + 2 < 16) W2_LOAD(rvA, tt + 2);
      W2_STORE(tb0, tt);
      W2_WRITE(tb1, rvB);
      ZCHUNK(tt);
      __syncthreads();
      if (tt + 3 < 16) W2_LOAD(rvB, tt + 3);
      W2_STORE(tb1, tt + 1);
      if (tt + 2 < 16) W2_WRITE(tb0, rvA);
      ZCHUNK(tt + 1);
      __syncthreads();
    }
#undef W2_LOAD
#undef W2_WRITE
#undef W2_STORE
#undef ZCHUNK
  }
}

// --- GEMM2 (R12-proven): 256m x 128n tile, 256 threads (4 waves, 2Mx2N),
//     BK=32, 3-slot LDS ring (72KB -> 2 blocks/CU), depth-2 prefetch with
//     counted vmcnt, 16x16x32 MFMA, XCD-chunked swizzle (1536 blocks),
//     per-t nt zero slice, LDS-transpose epilogue, nt 1KB slab stores. ---
__global__ __launch_bounds__(256, 2) void gemm2_pipe(
    const __hip_bfloat16* __restrict__ Aall,   // h_bf [12][2048][512]
    const __hip_bfloat16* __restrict__ Ball,   // W2T  [12][2048][512]
    const float* __restrict__ bias,            // b2   [12][2048]
    const float* __restrict__ cs,
    float* __restrict__ O,
    f32x4* __restrict__ zeroBase, int doZero) {
  __shared__ __hip_bfloat16 lds[3 * 12288];    // 3 slots x (A 16KB + B 8KB) = 72 KiB
  const int orig = blockIdx.x + 16 * blockIdx.y + 128 * blockIdx.z;   // x fastest
  const int nw   = (orig & 7) * 192 + (orig >> 3);   // bijective, 1536 % 8 == 0
  const int bx   = nw & 15;
  const int by   = (nw >> 4) & 7;
  const int l    = nw >> 7;
  const int n0  = bx * 128;
  const int m0  = by * 256;
  const int tid = threadIdx.x;
  const int wid = tid >> 6, lane = tid & 63;
  const int wm  = wid >> 1, wn = wid & 1;
  const __hip_bfloat16* A  = Aall + (size_t)l * MROWS * HID;
  const __hip_bfloat16* Bt = Ball + (size_t)l * ODIM * HID;
  f32x4* zq = zeroBase + (size_t)nw * 4096;    // 64KB slice of [0, 96MB)
  const f32x4 zv = {0.f, 0.f, 0.f, 0.f};

  f32x4 acc[8][4];
#pragma unroll
  for (int m = 0; m < 8; ++m)
#pragma unroll
    for (int n = 0; n < 4; ++n)
      acc[m][n] = {0.f, 0.f, 0.f, 0.f};

  int ra[4], ca[4], rb[2], cb[2];
#pragma unroll
  for (int j = 0; j < 4; ++j) {
    int cx = j * 256 + tid;
    ra[j] = cx >> 2; ca[j] = (cx & 3) ^ ((ra[j] >> 1) & 3);
  }
#pragma unroll
  for (int j = 0; j < 2; ++j) {
    int cx = j * 256 + tid;
    rb[j] = cx >> 2; cb[j] = (cx & 3) ^ ((rb[j] >> 1) & 3);
  }

#define STAGE_A(slot, kt) do {                                                      \
    _Pragma("unroll")                                                               \
    for (int j_ = 0; j_ < 4; ++j_)                                                  \
      gload_lds16(A + (size_t)(m0 + ra[j_]) * HID + (kt) * 32 + ca[j_] * 8,         \
                  lds + (slot) * 12288 + j_ * 2048 + wid * 512);                    \
  } while (0)
#define STAGE_B(slot, kt) do {                                                      \
    _Pragma("unroll")                                                               \
    for (int j_ = 0; j_ < 2; ++j_)                                                  \
      gload_lds16(Bt + (size_t)(n0 + rb[j_]) * HID + (kt) * 32 + cb[j_] * 8,        \
                  lds + (slot) * 12288 + 8192 + j_ * 2048 + wid * 512);             \
  } while (0)

  const int kq   = lane >> 4;
  const int rl15 = lane & 15;

#define LD_FRAG(dst, base, rr) do {                                                 \
    int r_ = (rr);                                                                  \
    int off_ = r_ * 64 + ((kq ^ ((r_ >> 1) & 3)) << 4);                             \
    dst = *(const short8*)((const char*)(base) + off_);                             \
  } while (0)

  // prologue: 2 tiles in flight (6 loads/thread per tile)
  STAGE_A(0, 0); STAGE_B(0, 0);
  STAGE_A(1, 1); STAGE_B(1, 1);
  asm volatile("s_waitcnt vmcnt(6)" ::: "memory");   // tile 0 landed
  __builtin_amdgcn_s_barrier();

  const int NT = HID / 32;   // 16
  for (int t = 0; t < NT; ++t) {
    const int cur = t % 3;
    const __hip_bfloat16* sa = lds + cur * 12288;
    const __hip_bfloat16* sb = sa + 8192;
    short8 af[4], bfr[4];

    if (doZero)
      __builtin_nontemporal_store(zv, zq + t * 256 + tid);

    // ---- phase 0: m-frags 0..3 ----
#pragma unroll
    for (int n = 0; n < 4; ++n) LD_FRAG(bfr[n], sb, wn * 64 + n * 16 + rl15);
#pragma unroll
    for (int mi = 0; mi < 4; ++mi) LD_FRAG(af[mi], sa, wm * 128 + mi * 16 + rl15);
    if (t + 2 < NT) STAGE_A((t + 2) % 3, t + 2);
    __builtin_amdgcn_s_barrier();
    __builtin_amdgcn_s_setprio(1);
#pragma unroll
    for (int mi = 0; mi < 4; ++mi)
#pragma unroll
      for (int n = 0; n < 4; ++n)
        acc[mi][n] = __builtin_amdgcn_mfma_f32_16x16x32_bf16(af[mi], bfr[n], acc[mi][n], 0, 0, 0);
    __builtin_amdgcn_s_setprio(0);
    __builtin_amdgcn_s_barrier();

    // ---- phase 1: m-frags 4..7 (bfr reused) ----
#pragma unroll
    for (int mi = 0; mi < 4; ++mi) LD_FRAG(af[mi], sa, wm * 128 + 64 + mi * 16 + rl15);
    if (t + 2 < NT) STAGE_B((t + 2) % 3, t + 2);
    __builtin_amdgcn_s_barrier();
    __builtin_amdgcn_s_setprio(1);
#pragma unroll
    for (int mi = 0; mi < 4; ++mi)
#pragma unroll
      for (int n = 0; n < 4; ++n)
        acc[4 + mi][n] = __builtin_amdgcn_mfma_f32_16x16x32_bf16(af[mi], bfr[n], acc[4 + mi][n], 0, 0, 0);
    __builtin_amdgcn_s_setprio(0);
    if (t < NT - 2)       asm volatile("s_waitcnt vmcnt(6)" ::: "memory");
    else if (t == NT - 2) asm volatile("s_waitcnt vmcnt(0)" ::: "memory");
    __builtin_amdgcn_s_barrier();
  }
#undef STAGE_A
#undef STAGE_B
#undef LD_FRAG

  // ---- epilogue: bias + RoPE in-reg, per-wave LDS transpose, nt 1KB stores ----
  __syncthreads();
  const int head = bx;
  const int tkv  = wn;
  const int bidx = by * 2 + wm;
  float* slab = O + ((((size_t)(l + L_ACT) * 2 + tkv) * BDIM + bidx) * NHEAD + head) * (PDIM * DHEAD);
  const bool ropeWave = (tkv == 0);

  float bb[4];
#pragma unroll
  for (int n = 0; n < 4; ++n) bb[n] = bias[l * ODIM + n0 + wn * 64 + n * 16 + rl15];

  float* Tw = (float*)lds + wid * 2080;   // 32 x 65 f32 per wave

#pragma unroll
  for (int c = 0; c < 4; ++c) {           // p-chunk [c*32, c*32+32)
#pragma unroll
    for (int mh = 0; mh < 2; ++mh) {
      int mf = c * 2 + mh;
      int pl = mh * 16 + (lane >> 4) * 4;
#pragma unroll
      for (int n = 0; n < 4; ++n) {
#pragma unroll
        for (int j = 0; j < 4; ++j) {
          float v = acc[mf][n][j] + bb[n];
          if (ropeWave && n == 0) {
            float partner = __shfl_xor(v, 8);
            int p = c * 32 + pl + j;
            float cv = cs[p * 8 + (lane & 7)];
            float sv = cs[1024 + p * 8 + (lane & 7)];
            v = v * cv + (((lane & 15) < 8) ? -partner : partner) * sv;
          }
          Tw[(pl + j) * 65 + n * 16 + rl15] = v;
        }
      }
    }
#pragma unroll
    for (int it = 0; it < 8; ++it) {
      int pl = it * 4 + (lane >> 4);
      f32x4 vv = *(const f32x4*)(Tw + pl * 65 + rl15 * 4);
      __builtin_nontemporal_store(vv, (f32x4*)(slab + (size_t)(c * 32 + pl) * DHEAD + rl15 * 4));
    }
  }
}

extern "C" void kernel_launch(void* const* d_in, const int* in_sizes, int n_in,
                              void* d_out, int out_size, void* d_ws, size_t ws_size,
                              hipStream_t stream) {
  const float* summary   = (const float*)d_in[0];
  const int*   positions = (const int*)d_in[1];
  const float* W1 = (const float*)d_in[2];
  const float* b1 = (const float*)d_in[3];
  const float* W2 = (const float*)d_in[4];
  const float* b2 = (const float*)d_in[5];
  float* out = (float*)d_out;

  // Scratch: h_bf 25165824 | W2T 25165824 | cs 8192
  const size_t SCRATCH_BYTES = 25165824ULL + 25165824ULL + 8192ULL;
  const bool useWs = (ws_size >= SCRATCH_BYTES);
  char* sc = useWs ? (char*)d_ws : (char*)d_out;
  __hip_bfloat16* h_bf = (__hip_bfloat16*)sc;
  __hip_bfloat16* W2T  = (__hip_bfloat16*)(sc + 25165824);
  float*          cs   = (float*)(sc + 50331648);

  // zero region split: gemm2 covers [0, 100663296), gemm1 covers the rest.
  gemm1_128<<<dim3(HID / 128, MROWS / 128, L_ACT), 256, 0, stream>>>(
      summary, W1, positions, b1, h_bf, W2, W2T, cs,
      (f32x4*)((char*)d_out + 100663296), useWs ? 1 : 0);
  gemm2_pipe<<<dim3(ODIM / 128, MROWS / 256, L_ACT), 256, 0, stream>>>(
      h_bf, W2T, b2, cs, out, (f32x4*)d_out, useWs ? 1 : 0);

  if (!useWs)   // scratch aliased d_out: zero AFTER gemm2 has consumed it
    zerofill_kernel<<<2048, 256, 0, stream>>>((f32x4*)d_out, 12582912);
}

// Round 15
// 121.422 us; speedup vs baseline: 1.2059x; 1.0248x over previous
//
#include <hip/hip_runtime.h>
#include <hip/hip_bf16.h>

// Problem constants
#define L_ACT   12
#define BDIM    16
#define PDIM    128
#define DSUM    128
#define HID     512
#define ODIM    2048
#define NHEAD   16
#define DHEAD   64
#define MROWS   2048   // B*P rows per layer

typedef short s16x4  __attribute__((ext_vector_type(4)));
typedef short short8 __attribute__((ext_vector_type(8)));
typedef float f32x4  __attribute__((ext_vector_type(4)));

__device__ __forceinline__ void gload_lds16(const __hip_bfloat16* g, __hip_bfloat16* l) {
  __builtin_amdgcn_global_load_lds(
      (const __attribute__((address_space(1))) unsigned int*)g,
      (__attribute__((address_space(3))) unsigned int*)l, 16, 0, 0);
}

__device__ __forceinline__ short f2bf(float x) {
  __hip_bfloat16 h = __float2bfloat16(x);
  return *reinterpret_cast<short*>(&h);
}

// LDS-only barrier: gemm1's barriers order LDS state only; skipping the
// vmcnt(0) drain lets stores/prefetch loads pipeline across barriers.
#define LBAR() do {                                                   \
    asm volatile("s_waitcnt lgkmcnt(0)" ::: "memory");                \
    __builtin_amdgcn_s_barrier();                                     \
  } while (0)

// --- zero-fill (fallback path only) ---
__global__ __launch_bounds__(256) void zerofill_kernel(f32x4* __restrict__ p, int n16) {
  int stride = gridDim.x * 256;
  for (int i = blockIdx.x * 256 + threadIdx.x; i < n16; i += stride)
    p[i] = {0.f, 0.f, 0.f, 0.f};
}

// --- GEMM1: 128x128 tile, 4 waves, bias+relu, bf16 out.
//     A staged per-kt from f32 summary; B staged once per block from f32 W1
//     (persistent full-K swizzled tile). Block 0 computes cos/sin table.
//     H via LDS transpose; fused pipelined W2 -> W2T transpose.
//     All barriers are LDS-only (no vmcnt drain); W2-tail loads pre-issued
//     before the K-loop; 128KB nt zero-fill spread across all phases. ---
__global__ __launch_bounds__(256) void gemm1_128(
    const float* __restrict__ summary,          // [2048][128] f32
    const float* __restrict__ W1,               // [12][128][512] f32
    const int*   __restrict__ positions,
    const float* __restrict__ bias,
    __hip_bfloat16* __restrict__ Hall,
    const float* __restrict__ W2,
    __hip_bfloat16* __restrict__ W2T,
    float* __restrict__ cs,
    f32x4* __restrict__ zeroBase, int doZero) {
  const int KTOT = DSUM, NTOT = HID;
  __shared__ __hip_bfloat16 shbuf[24576];   // 49152B: B2 32KB | A 16KB (H tile reuses)
  __hip_bfloat16* ldsB2 = shbuf;            // [128 r][256B] full-K swizzled B tile
  __hip_bfloat16* ldsA  = shbuf + 16384;    // per-kt A tile [128 r][128B]
  const int l    = blockIdx.z;
  const int n0   = blockIdx.x * 128;
  const int m0   = blockIdx.y * 128;
  const int tid  = threadIdx.x;
  const int wid  = tid >> 6;
  const int lane = tid & 63;
  const int wr = wid >> 1, wc = wid & 1;
  const int bid = blockIdx.x + 4 * blockIdx.y + 64 * blockIdx.z;   // 0..767

  const f32x4 z = {0.f, 0.f, 0.f, 0.f};
  f32x4* zp = zeroBase + (size_t)bid * 8192;   // 128KB chunk, slots 0..8191

  // block 0: cos/sin table (consumed by gemm2; stream order guarantees visibility)
  if (bid == 0) {
#pragma unroll
    for (int q = 0; q < 4; ++q) {
      int i = q * 256 + tid;
      int p = i >> 3, f = i & 7;
      double inv = pow(10000.0, -(double)f / 8.0);
      double ang = (double)positions[p] * inv;
      cs[i]        = (float)cos(ang);
      cs[1024 + i] = (float)sin(ang);
    }
  }

  // W2-tail load macros (defined early; first two tiles pre-issued pre-K-loop)
  const int tx = tid & 31, ty = tid >> 5;
  const int tbase = bid * 16;
  float rvA0, rvA1, rvA2, rvA3, rvB0, rvB1, rvB2, rvB3;

#define W2_LOAD(P, tt_) do {                                                \
      int t_ = tbase + (tt_);                                               \
      int lz_ = t_ >> 10, rem_ = t_ & 1023;                                 \
      int j0_ = (rem_ >> 6) * 32, o0_ = (rem_ & 63) * 32;                   \
      const float* ip_ = W2 + (size_t)lz_ * HID * ODIM                      \
                       + (size_t)(j0_ + ty) * ODIM + o0_ + tx;              \
      P##0 = ip_[0];                                                        \
      P##1 = ip_[(size_t)8 * ODIM];                                         \
      P##2 = ip_[(size_t)16 * ODIM];                                        \
      P##3 = ip_[(size_t)24 * ODIM];                                        \
    } while (0)

  // B2 staging: W1[l][j][n0+r] -> ldsB2[r][(j4>>1)^(r&7)][j4&1]
  {
    const float* Wp = W1 + (size_t)l * DSUM * HID + n0;
#pragma unroll
    for (int q = 0; q < 16; ++q) {
      int g  = q * 256 + tid;
      int j4 = g >> 7;            // 0..31 (4 consecutive j)
      int r  = g & 127;
      s16x4 w;
#pragma unroll
      for (int jj = 0; jj < 4; ++jj)
        w[jj] = f2bf(Wp[(size_t)(j4 * 4 + jj) * HID + r]);
      int chunk = (j4 >> 1) ^ (r & 7);
      *(s16x4*)((char*)ldsB2 + r * 256 + chunk * 16 + (j4 & 1) * 8) = w;
    }
  }

  // pre-issue W2-tail tiles 0,1: HBM latency hides under K-loop + H epilogue
  W2_LOAD(rvA, 0);
  W2_LOAD(rvB, 1);

  f32x4 acc[4][4];
#pragma unroll
  for (int m = 0; m < 4; ++m)
#pragma unroll
    for (int n = 0; n < 4; ++n)
      acc[m][n] = {0.f, 0.f, 0.f, 0.f};

  const int kq = lane >> 4;

  for (int kt = 0; kt < KTOT / 64; ++kt) {
    LBAR();   // kt=0: orders B2 writes before reads; also guards ldsA reuse
    // zero slice during latency-bound staging phase (slots 0..2047)
    if (doZero) {
#pragma unroll
      for (int q = 0; q < 4; ++q)
        __builtin_nontemporal_store(z, zp + (kt * 4 + q) * 256 + tid);
    }
    // A: reg-staged f32 -> bf16, swizzled ds_write_b64
#pragma unroll
    for (int j = 0; j < 8; ++j) {
      int s = j * 256 + tid;
      int r = s >> 4, g = s & 15;
      f32x4 v = *(const f32x4*)(summary + (size_t)(m0 + r) * DSUM + kt * 64 + g * 4);
      s16x4 w;
      w[0] = f2bf(v[0]); w[1] = f2bf(v[1]); w[2] = f2bf(v[2]); w[3] = f2bf(v[3]);
      int ch = g >> 1;
      *(s16x4*)((char*)ldsA + r * 128 + ((ch ^ (r & 7)) << 4) + (g & 1) * 8) = w;
    }
    LBAR();
#pragma unroll
    for (int kk = 0; kk < 2; ++kk) {
      short8 af[4], bfr[4];
#pragma unroll
      for (int m = 0; m < 4; ++m) {
        int row = wr * 64 + m * 16 + (lane & 15);
        int off = (kk * 64 + kq * 16) ^ ((row & 7) << 4);
        af[m] = *(const short8*)((const char*)ldsA + row * 128 + off);
      }
#pragma unroll
      for (int n = 0; n < 4; ++n) {
        int row = wc * 64 + n * 16 + (lane & 15);
        int chunk = (kt * 8 + kk * 4 + kq) ^ (row & 7);
        bfr[n] = *(const short8*)((const char*)ldsB2 + row * 256 + chunk * 16);
      }
#pragma unroll
      for (int m = 0; m < 4; ++m)
#pragma unroll
        for (int n = 0; n < 4; ++n)
          acc[m][n] = __builtin_amdgcn_mfma_f32_16x16x32_bf16(af[m], bfr[n], acc[m][n], 0, 0, 0);
    }
  }

  // H epilogue via LDS: [128][136] bf16 padded tile -> 256B-run stores
  LBAR();   // all waves done reading B2/A staging
#pragma unroll
  for (int n = 0; n < 4; ++n) {
    int col = wc * 64 + n * 16 + (lane & 15);
    float bb = bias[l * NTOT + n0 + col];
#pragma unroll
    for (int m = 0; m < 4; ++m) {
      int rowb = wr * 64 + m * 16 + ((lane >> 4) << 2);
#pragma unroll
      for (int j = 0; j < 4; ++j) {
        float v = acc[m][n][j] + bb;
        v = v > 0.f ? v : 0.f;
        shbuf[(rowb + j) * 136 + col] = __float2bfloat16(v);
      }
    }
  }
  // zero slice during H scatter (slots 2048..4095)
  if (doZero) {
#pragma unroll
    for (int i = 0; i < 8; ++i)
      __builtin_nontemporal_store(z, zp + (8 + i) * 256 + tid);
  }
  LBAR();
  {
    __hip_bfloat16* H = Hall + (size_t)l * MROWS * HID;
#pragma unroll
    for (int i = 0; i < 8; ++i) {
      int idx = i * 256 + tid;
      int row = idx >> 4, seg = idx & 15;
      short8 v = *(const short8*)(shbuf + row * 136 + seg * 8);
      *(short8*)(H + (size_t)(m0 + row) * HID + n0 + seg * 8) = v;
    }
  }
  LBAR();   // H LDS reads done before W2 section overwrites shbuf

  // fused W2 -> W2T transpose, pipelined (dbuf LDS, 2-deep reg prefetch,
  // 1 LDS-only barrier/tile) with interleaved nt zero-fill (tiles 0..3).
  {
    float* tb0 = (float*)shbuf;            // 32x33 f32 = 4224B
    float* tb1 = (float*)shbuf + 1056;

#define W2_WRITE(buf, P) do {                                               \
      (buf)[(ty +  0) * 33 + tx] = P##0;                                    \
      (buf)[(ty +  8) * 33 + tx] = P##1;                                    \
      (buf)[(ty + 16) * 33 + tx] = P##2;                                    \
      (buf)[(ty + 24) * 33 + tx] = P##3;                                    \
    } while (0)

#define W2_STORE(buf, tt_) do {                                             \
      int t_ = tbase + (tt_);                                               \
      int lz_ = t_ >> 10, rem_ = t_ & 1023;                                 \
      int j0_ = (rem_ >> 6) * 32, o0_ = (rem_ & 63) * 32;                   \
      __hip_bfloat16* op_ = W2T + (size_t)lz_ * HID * ODIM;                 \
      _Pragma("unroll")                                                     \
      for (int r_ = 0; r_ < 4; ++r_)                                        \
        op_[(size_t)(o0_ + ty + 8 * r_) * HID + j0_ + tx] =                 \
            __float2bfloat16((buf)[tx * 33 + ty + 8 * r_]);                 \
    } while (0)

#define ZCHUNK(tt_) do { if (doZero && (tt_) < 4) {                         \
      _Pragma("unroll")                                                     \
      for (int q_ = 0; q_ < 4; ++q_)                                        \
        __builtin_nontemporal_store(z, zp + (16 + (tt_) * 4 + q_) * 256 + tid); \
    } } while (0)

    W2_WRITE(tb0, rvA);
    LBAR();
#pragma unroll 1
    for (int tt = 0; tt < 16; tt += 2) {
      if (tt + 2 < 16) W2_LOAD(rvA, tt + 2);
      W2_STORE(tb0, tt);
      W2_WRITE(tb1, rvB);
      ZCHUNK(tt);
      LBAR();
      if (tt + 3 < 16) W2_LOAD(rvB, tt + 3);
      W2_STORE(tb1, tt + 1);
      if (tt + 2 < 16) W2_WRITE(tb0, rvA);
      ZCHUNK(tt + 1);
      LBAR();
    }
#undef W2_LOAD
#undef W2_WRITE
#undef W2_STORE
#undef ZCHUNK
  }
}

// --- GEMM2 (R12-proven, untouched): 256m x 128n tile, 256 threads (4 waves,
//     2Mx2N), BK=32, 3-slot LDS ring (72KB -> 2 blocks/CU), depth-2 prefetch
//     with counted vmcnt, 16x16x32 MFMA, XCD-chunked swizzle (1536 blocks),
//     per-t nt zero slice, LDS-transpose epilogue, nt 1KB slab stores. ---
__global__ __launch_bounds__(256, 2) void gemm2_pipe(
    const __hip_bfloat16* __restrict__ Aall,   // h_bf [12][2048][512]
    const __hip_bfloat16* __restrict__ Ball,   // W2T  [12][2048][512]
    const float* __restrict__ bias,            // b2   [12][2048]
    const float* __restrict__ cs,
    float* __restrict__ O,
    f32x4* __restrict__ zeroBase, int doZero) {
  __shared__ __hip_bfloat16 lds[3 * 12288];    // 3 slots x (A 16KB + B 8KB) = 72 KiB
  const int orig = blockIdx.x + 16 * blockIdx.y + 128 * blockIdx.z;   // x fastest
  const int nw   = (orig & 7) * 192 + (orig >> 3);   // bijective, 1536 % 8 == 0
  const int bx   = nw & 15;
  const int by   = (nw >> 4) & 7;
  const int l    = nw >> 7;
  const int n0  = bx * 128;
  const int m0  = by * 256;
  const int tid = threadIdx.x;
  const int wid = tid >> 6, lane = tid & 63;
  const int wm  = wid >> 1, wn = wid & 1;
  const __hip_bfloat16* A  = Aall + (size_t)l * MROWS * HID;
  const __hip_bfloat16* Bt = Ball + (size_t)l * ODIM * HID;
  f32x4* zq = zeroBase + (size_t)nw * 4096;    // 64KB slice of [0, 96MB)
  const f32x4 zv = {0.f, 0.f, 0.f, 0.f};

  f32x4 acc[8][4];
#pragma unroll
  for (int m = 0; m < 8; ++m)
#pragma unroll
    for (int n = 0; n < 4; ++n)
      acc[m][n] = {0.f, 0.f, 0.f, 0.f};

  int ra[4], ca[4], rb[2], cb[2];
#pragma unroll
  for (int j = 0; j < 4; ++j) {
    int cx = j * 256 + tid;
    ra[j] = cx >> 2; ca[j] = (cx & 3) ^ ((ra[j] >> 1) & 3);
  }
#pragma unroll
  for (int j = 0; j < 2; ++j) {
    int cx = j * 256 + tid;
    rb[j] = cx >> 2; cb[j] = (cx & 3) ^ ((rb[j] >> 1) & 3);
  }

#define STAGE_A(slot, kt) do {                                                      \
    _Pragma("unroll")                                                               \
    for (int j_ = 0; j_ < 4; ++j_)                                                  \
      gload_lds16(A + (size_t)(m0 + ra[j_]) * HID + (kt) * 32 + ca[j_] * 8,         \
                  lds + (slot) * 12288 + j_ * 2048 + wid * 512);                    \
  } while (0)
#define STAGE_B(slot, kt) do {                                                      \
    _Pragma("unroll")                                                               \
    for (int j_ = 0; j_ < 2; ++j_)                                                  \
      gload_lds16(Bt + (size_t)(n0 + rb[j_]) * HID + (kt) * 32 + cb[j_] * 8,        \
                  lds + (slot) * 12288 + 8192 + j_ * 2048 + wid * 512);             \
  } while (0)

  const int kq   = lane >> 4;
  const int rl15 = lane & 15;

#define LD_FRAG(dst, base, rr) do {                                                 \
    int r_ = (rr);                                                                  \
    int off_ = r_ * 64 + ((kq ^ ((r_ >> 1) & 3)) << 4);                             \
    dst = *(const short8*)((const char*)(base) + off_);                             \
  } while (0)

  // prologue: 2 tiles in flight (6 loads/thread per tile)
  STAGE_A(0, 0); STAGE_B(0, 0);
  STAGE_A(1, 1); STAGE_B(1, 1);
  asm volatile("s_waitcnt vmcnt(6)" ::: "memory");   // tile 0 landed
  __builtin_amdgcn_s_barrier();

  const int NT = HID / 32;   // 16
  for (int t = 0; t < NT; ++t) {
    const int cur = t % 3;
    const __hip_bfloat16* sa = lds + cur * 12288;
    const __hip_bfloat16* sb = sa + 8192;
    short8 af[4], bfr[4];

    if (doZero)
      __builtin_nontemporal_store(zv, zq + t * 256 + tid);

    // ---- phase 0: m-frags 0..3 ----
#pragma unroll
    for (int n = 0; n < 4; ++n) LD_FRAG(bfr[n], sb, wn * 64 + n * 16 + rl15);
#pragma unroll
    for (int mi = 0; mi < 4; ++mi) LD_FRAG(af[mi], sa, wm * 128 + mi * 16 + rl15);
    if (t + 2 < NT) STAGE_A((t + 2) % 3, t + 2);
    __builtin_amdgcn_s_barrier();
    __builtin_amdgcn_s_setprio(1);
#pragma unroll
    for (int mi = 0; mi < 4; ++mi)
#pragma unroll
      for (int n = 0; n < 4; ++n)
        acc[mi][n] = __builtin_amdgcn_mfma_f32_16x16x32_bf16(af[mi], bfr[n], acc[mi][n], 0, 0, 0);
    __builtin_amdgcn_s_setprio(0);
    __builtin_amdgcn_s_barrier();

    // ---- phase 1: m-frags 4..7 (bfr reused) ----
#pragma unroll
    for (int mi = 0; mi < 4; ++mi) LD_FRAG(af[mi], sa, wm * 128 + 64 + mi * 16 + rl15);
    if (t + 2 < NT) STAGE_B((t + 2) % 3, t + 2);
    __builtin_amdgcn_s_barrier();
    __builtin_amdgcn_s_setprio(1);
#pragma unroll
    for (int mi = 0; mi < 4; ++mi)
#pragma unroll
      for (int n = 0; n < 4; ++n)
        acc[4 + mi][n] = __builtin_amdgcn_mfma_f32_16x16x32_bf16(af[mi], bfr[n], acc[4 + mi][n], 0, 0, 0);
    __builtin_amdgcn_s_setprio(0);
    if (t < NT - 2)       asm volatile("s_waitcnt vmcnt(6)" ::: "memory");
    else if (t == NT - 2) asm volatile("s_waitcnt vmcnt(0)" ::: "memory");
    __builtin_amdgcn_s_barrier();
  }
#undef STAGE_A
#undef STAGE_B
#undef LD_FRAG

  // ---- epilogue: bias + RoPE in-reg, per-wave LDS transpose, nt 1KB stores ----
  __syncthreads();
  const int head = bx;
  const int tkv  = wn;
  const int bidx = by * 2 + wm;
  float* slab = O + ((((size_t)(l + L_ACT) * 2 + tkv) * BDIM + bidx) * NHEAD + head) * (PDIM * DHEAD);
  const bool ropeWave = (tkv == 0);

  float bb[4];
#pragma unroll
  for (int n = 0; n < 4; ++n) bb[n] = bias[l * ODIM + n0 + wn * 64 + n * 16 + rl15];

  float* Tw = (float*)lds + wid * 2080;   // 32 x 65 f32 per wave

#pragma unroll
  for (int c = 0; c < 4; ++c) {           // p-chunk [c*32, c*32+32)
#pragma unroll
    for (int mh = 0; mh < 2; ++mh) {
      int mf = c * 2 + mh;
      int pl = mh * 16 + (lane >> 4) * 4;
#pragma unroll
      for (int n = 0; n < 4; ++n) {
#pragma unroll
        for (int j = 0; j < 4; ++j) {
          float v = acc[mf][n][j] + bb[n];
          if (ropeWave && n == 0) {
            float partner = __shfl_xor(v, 8);
            int p = c * 32 + pl + j;
            float cv = cs[p * 8 + (lane & 7)];
            float sv = cs[1024 + p * 8 + (lane & 7)];
            v = v * cv + (((lane & 15) < 8) ? -partner : partner) * sv;
          }
          Tw[(pl + j) * 65 + n * 16 + rl15] = v;
        }
      }
    }
#pragma unroll
    for (int it = 0; it < 8; ++it) {
      int pl = it * 4 + (lane >> 4);
      f32x4 vv = *(const f32x4*)(Tw + pl * 65 + rl15 * 4);
      __builtin_nontemporal_store(vv, (f32x4*)(slab + (size_t)(c * 32 + pl) * DHEAD + rl15 * 4));
    }
  }
}

extern "C" void kernel_launch(void* const* d_in, const int* in_sizes, int n_in,
                              void* d_out, int out_size, void* d_ws, size_t ws_size,
                              hipStream_t stream) {
  const float* summary   = (const float*)d_in[0];
  const int*   positions = (const int*)d_in[1];
  const float* W1 = (const float*)d_in[2];
  const float* b1 = (const float*)d_in[3];
  const float* W2 = (const float*)d_in[4];
  const float* b2 = (const float*)d_in[5];
  float* out = (float*)d_out;

  // Scratch: h_bf 25165824 | W2T 25165824 | cs 8192
  const size_t SCRATCH_BYTES = 25165824ULL + 25165824ULL + 8192ULL;
  const bool useWs = (ws_size >= SCRATCH_BYTES);
  char* sc = useWs ? (char*)d_ws : (char*)d_out;
  __hip_bfloat16* h_bf = (__hip_bfloat16*)sc;
  __hip_bfloat16* W2T  = (__hip_bfloat16*)(sc + 25165824);
  float*          cs   = (float*)(sc + 50331648);

  // zero region split: gemm2 covers [0, 100663296), gemm1 covers the rest.
  gemm1_128<<<dim3(HID / 128, MROWS / 128, L_ACT), 256, 0, stream>>>(
      summary, W1, positions, b1, h_bf, W2, W2T, cs,
      (f32x4*)((char*)d_out + 100663296), useWs ? 1 : 0);
  gemm2_pipe<<<dim3(ODIM / 128, MROWS / 256, L_ACT), 256, 0, stream>>>(
      h_bf, W2T, b2, cs, out, (f32x4*)d_out, useWs ? 1 : 0);

  if (!useWs)   // scratch aliased d_out: zero AFTER gemm2 has consumed it
    zerofill_kernel<<<2048, 256, 0, stream>>>((f32x4*)d_out, 12582912);
}

// Round 16
// 118.010 us; speedup vs baseline: 1.2407x; 1.0289x over previous
//
#include <hip/hip_runtime.h>
#include <hip/hip_bf16.h>

// Problem constants
#define L_ACT   12
#define BDIM    16
#define PDIM    128
#define DSUM    128
#define HID     512
#define ODIM    2048
#define NHEAD   16
#define DHEAD   64
#define MROWS   2048   // B*P rows per layer

typedef short s16x4  __attribute__((ext_vector_type(4)));
typedef short short8 __attribute__((ext_vector_type(8)));
typedef float f32x4  __attribute__((ext_vector_type(4)));

__device__ __forceinline__ void gload_lds16(const __hip_bfloat16* g, __hip_bfloat16* l) {
  __builtin_amdgcn_global_load_lds(
      (const __attribute__((address_space(1))) unsigned int*)g,
      (__attribute__((address_space(3))) unsigned int*)l, 16, 0, 0);
}

__device__ __forceinline__ short f2bf(float x) {
  __hip_bfloat16 h = __float2bfloat16(x);
  return *reinterpret_cast<short*>(&h);
}

// LDS-only barrier: gemm1's barriers order LDS state only; skipping the
// vmcnt(0) drain lets stores/prefetch loads pipeline across barriers.
#define LBAR() do {                                                   \
    asm volatile("s_waitcnt lgkmcnt(0)" ::: "memory");                \
    __builtin_amdgcn_s_barrier();                                     \
  } while (0)

// --- zero-fill (fallback path only) ---
__global__ __launch_bounds__(256) void zerofill_kernel(f32x4* __restrict__ p, int n16) {
  int stride = gridDim.x * 256;
  for (int i = blockIdx.x * 256 + threadIdx.x; i < n16; i += stride)
    p[i] = {0.f, 0.f, 0.f, 0.f};
}

// --- GEMM1: 128x128 tile, 4 waves, bias+relu, bf16 out.
//     A staged per-kt from f32 summary; B staged once per block from f32 W1
//     (persistent full-K swizzled tile). Block 0 computes cos/sin table.
//     H via LDS transpose; fused pipelined W2 -> W2T transpose with 64x64
//     tiles (256B read runs / 128B write runs, granule-XOR-swizzled LDS).
//     All barriers LDS-only; W2-tail loads pre-issued before the K-loop;
//     128KB nt zero-fill spread across all phases. ---
__global__ __launch_bounds__(256) void gemm1_128(
    const float* __restrict__ summary,          // [2048][128] f32
    const float* __restrict__ W1,               // [12][128][512] f32
    const int*   __restrict__ positions,
    const float* __restrict__ bias,
    __hip_bfloat16* __restrict__ Hall,
    const float* __restrict__ W2,
    __hip_bfloat16* __restrict__ W2T,
    float* __restrict__ cs,
    f32x4* __restrict__ zeroBase, int doZero) {
  const int KTOT = DSUM, NTOT = HID;
  __shared__ __hip_bfloat16 shbuf[24576];   // 49152B: B2 32KB | A 16KB (tail reuses)
  __hip_bfloat16* ldsB2 = shbuf;            // [128 r][256B] full-K swizzled B tile
  __hip_bfloat16* ldsA  = shbuf + 16384;    // per-kt A tile [128 r][128B]
  const int l    = blockIdx.z;
  const int n0   = blockIdx.x * 128;
  const int m0   = blockIdx.y * 128;
  const int tid  = threadIdx.x;
  const int wid  = tid >> 6;
  const int lane = tid & 63;
  const int wr = wid >> 1, wc = wid & 1;
  const int bid = blockIdx.x + 4 * blockIdx.y + 64 * blockIdx.z;   // 0..767

  const f32x4 z = {0.f, 0.f, 0.f, 0.f};
  f32x4* zp = zeroBase + (size_t)bid * 8192;   // 128KB chunk, slot groups 0..31

  // block 0: cos/sin table (consumed by gemm2; stream order guarantees visibility)
  if (bid == 0) {
#pragma unroll
    for (int q = 0; q < 4; ++q) {
      int i = q * 256 + tid;
      int p = i >> 3, f = i & 7;
      double inv = pow(10000.0, -(double)f / 8.0);
      double ang = (double)positions[p] * inv;
      cs[i]        = (float)cos(ang);
      cs[1024 + i] = (float)sin(ang);
    }
  }

  // W2-tail geometry: 4 tiles/block of 64j x 64o; reads 256B runs, writes 128B runs
  const int rowg = tid >> 4;          // 0..15 (j rows, +16p)
  const int colg = tid & 15;          // o granule (4 f32)
  const int orow = tid >> 3;          // 0..31 (o rows for store, +32p)
  const int jg   = tid & 7;           // j granule (8 bf16) for store
  const int tbase4 = bid * 4;
  f32x4 rvA0, rvA1, rvA2, rvA3, rvB0, rvB1, rvB2, rvB3;

#define W2_LOAD(P, tt_) do {                                                \
      int t_ = tbase4 + (tt_);                                              \
      int lz_ = t_ >> 8, rem_ = t_ & 255;                                   \
      int j0_ = (rem_ >> 5) * 64, o0_ = (rem_ & 31) * 64;                   \
      const float* ip_ = W2 + (size_t)lz_ * HID * ODIM                      \
                       + (size_t)(j0_ + rowg) * ODIM + o0_ + colg * 4;      \
      P##0 = *(const f32x4*)(ip_);                                          \
      P##1 = *(const f32x4*)(ip_ + (size_t)16 * ODIM);                      \
      P##2 = *(const f32x4*)(ip_ + (size_t)32 * ODIM);                      \
      P##3 = *(const f32x4*)(ip_ + (size_t)48 * ODIM);                      \
    } while (0)

  // B2 staging: W1[l][j][n0+r] -> ldsB2[r][(j4>>1)^(r&7)][j4&1]
  {
    const float* Wp = W1 + (size_t)l * DSUM * HID + n0;
#pragma unroll
    for (int q = 0; q < 16; ++q) {
      int g  = q * 256 + tid;
      int j4 = g >> 7;            // 0..31 (4 consecutive j)
      int r  = g & 127;
      s16x4 w;
#pragma unroll
      for (int jj = 0; jj < 4; ++jj)
        w[jj] = f2bf(Wp[(size_t)(j4 * 4 + jj) * HID + r]);
      int chunk = (j4 >> 1) ^ (r & 7);
      *(s16x4*)((char*)ldsB2 + r * 256 + chunk * 16 + (j4 & 1) * 8) = w;
    }
  }

  // pre-issue W2-tail tiles 0,1: HBM latency hides under K-loop + H epilogue
  W2_LOAD(rvA, 0);
  W2_LOAD(rvB, 1);

  f32x4 acc[4][4];
#pragma unroll
  for (int m = 0; m < 4; ++m)
#pragma unroll
    for (int n = 0; n < 4; ++n)
      acc[m][n] = {0.f, 0.f, 0.f, 0.f};

  const int kq = lane >> 4;

  for (int kt = 0; kt < KTOT / 64; ++kt) {
    LBAR();   // kt=0: orders B2 writes before reads; also guards ldsA reuse
    // zero slice during staging phase (slot groups 0..7)
    if (doZero) {
#pragma unroll
      for (int q = 0; q < 4; ++q)
        __builtin_nontemporal_store(z, zp + (kt * 4 + q) * 256 + tid);
    }
    // A: reg-staged f32 -> bf16, swizzled ds_write_b64
#pragma unroll
    for (int j = 0; j < 8; ++j) {
      int s = j * 256 + tid;
      int r = s >> 4, g = s & 15;
      f32x4 v = *(const f32x4*)(summary + (size_t)(m0 + r) * DSUM + kt * 64 + g * 4);
      s16x4 w;
      w[0] = f2bf(v[0]); w[1] = f2bf(v[1]); w[2] = f2bf(v[2]); w[3] = f2bf(v[3]);
      int ch = g >> 1;
      *(s16x4*)((char*)ldsA + r * 128 + ((ch ^ (r & 7)) << 4) + (g & 1) * 8) = w;
    }
    LBAR();
#pragma unroll
    for (int kk = 0; kk < 2; ++kk) {
      short8 af[4], bfr[4];
#pragma unroll
      for (int m = 0; m < 4; ++m) {
        int row = wr * 64 + m * 16 + (lane & 15);
        int off = (kk * 64 + kq * 16) ^ ((row & 7) << 4);
        af[m] = *(const short8*)((const char*)ldsA + row * 128 + off);
      }
#pragma unroll
      for (int n = 0; n < 4; ++n) {
        int row = wc * 64 + n * 16 + (lane & 15);
        int chunk = (kt * 8 + kk * 4 + kq) ^ (row & 7);
        bfr[n] = *(const short8*)((const char*)ldsB2 + row * 256 + chunk * 16);
      }
#pragma unroll
      for (int m = 0; m < 4; ++m)
#pragma unroll
        for (int n = 0; n < 4; ++n)
          acc[m][n] = __builtin_amdgcn_mfma_f32_16x16x32_bf16(af[m], bfr[n], acc[m][n], 0, 0, 0);
    }
  }

  // H epilogue via LDS: [128][136] bf16 padded tile -> 256B-run stores
  LBAR();   // all waves done reading B2/A staging
#pragma unroll
  for (int n = 0; n < 4; ++n) {
    int col = wc * 64 + n * 16 + (lane & 15);
    float bb = bias[l * NTOT + n0 + col];
#pragma unroll
    for (int m = 0; m < 4; ++m) {
      int rowb = wr * 64 + m * 16 + ((lane >> 4) << 2);
#pragma unroll
      for (int j = 0; j < 4; ++j) {
        float v = acc[m][n][j] + bb;
        v = v > 0.f ? v : 0.f;
        shbuf[(rowb + j) * 136 + col] = __float2bfloat16(v);
      }
    }
  }
  // zero slice during H scatter (slot groups 8..15)
  if (doZero) {
#pragma unroll
    for (int i = 0; i < 8; ++i)
      __builtin_nontemporal_store(z, zp + (8 + i) * 256 + tid);
  }
  LBAR();
  {
    __hip_bfloat16* H = Hall + (size_t)l * MROWS * HID;
#pragma unroll
    for (int i = 0; i < 8; ++i) {
      int idx = i * 256 + tid;
      int row = idx >> 4, seg = idx & 15;
      short8 v = *(const short8*)(shbuf + row * 136 + seg * 8);
      *(short8*)(H + (size_t)(m0 + row) * HID + n0 + seg * 8) = v;
    }
  }
  LBAR();   // H LDS reads done before W2 section overwrites shbuf

  // fused W2 -> W2T transpose: 4 x (64j x 64o) tiles, dbuf [64][68] f32 with
  // granule-XOR swizzle (col4' = col4 ^ (j>>3)), 2-deep reg prefetch,
  // 1 LDS-only barrier/tile, interleaved nt zero-fill (slot groups 16..31).
  {
    float* tb0 = (float*)shbuf;            // 64x68 f32 = 17408B
    float* tb1 = (float*)shbuf + 4352;

#define W2_WRITE(buf, P) do {                                               \
      _Pragma("unroll")                                                     \
      for (int p_ = 0; p_ < 4; ++p_) {                                      \
        int j_ = rowg + 16 * p_;                                            \
        f32x4 vv_ = (p_ == 0) ? P##0 : (p_ == 1) ? P##1 : (p_ == 2) ? P##2 : P##3; \
        *(f32x4*)&(buf)[j_ * 68 + 4 * (colg ^ (j_ >> 3))] = vv_;            \
      }                                                                     \
    } while (0)

#define W2_STORE(buf, tt_) do {                                             \
      int t_ = tbase4 + (tt_);                                              \
      int lz_ = t_ >> 8, rem_ = t_ & 255;                                   \
      int j0_ = (rem_ >> 5) * 64, o0_ = (rem_ & 31) * 64;                   \
      __hip_bfloat16* op_ = W2T + (size_t)lz_ * HID * ODIM;                 \
      _Pragma("unroll")                                                     \
      for (int p_ = 0; p_ < 2; ++p_) {                                      \
        int or_ = orow + 32 * p_;                                           \
        short8 w_;                                                          \
        _Pragma("unroll")                                                   \
        for (int i_ = 0; i_ < 8; ++i_)                                      \
          w_[i_] = f2bf((buf)[(jg * 8 + i_) * 68 + (or_ ^ (4 * jg))]);      \
        *(short8*)(op_ + (size_t)(o0_ + or_) * HID + j0_ + jg * 8) = w_;    \
      }                                                                     \
    } while (0)

#define ZCHUNK(tt_) do { if (doZero) {                                      \
      _Pragma("unroll")                                                     \
      for (int q_ = 0; q_ < 4; ++q_)                                        \
        __builtin_nontemporal_store(z, zp + (16 + (tt_) * 4 + q_) * 256 + tid); \
    } } while (0)

    W2_WRITE(tb0, rvA);
    LBAR();
#pragma unroll 1
    for (int tt = 0; tt < 4; tt += 2) {
      if (tt + 2 < 4) W2_LOAD(rvA, tt + 2);
      W2_STORE(tb0, tt);
      W2_WRITE(tb1, rvB);
      ZCHUNK(tt);
      LBAR();
      if (tt + 3 < 4) W2_LOAD(rvB, tt + 3);
      W2_STORE(tb1, tt + 1);
      if (tt + 2 < 4) W2_WRITE(tb0, rvA);
      ZCHUNK(tt + 1);
      LBAR();
    }
#undef W2_LOAD
#undef W2_WRITE
#undef W2_STORE
#undef ZCHUNK
  }
}

// --- GEMM2 (R12-proven, untouched): 256m x 128n tile, 256 threads (4 waves,
//     2Mx2N), BK=32, 3-slot LDS ring (72KB -> 2 blocks/CU), depth-2 prefetch
//     with counted vmcnt, 16x16x32 MFMA, XCD-chunked swizzle (1536 blocks),
//     per-t nt zero slice, LDS-transpose epilogue, nt 1KB slab stores. ---
__global__ __launch_bounds__(256, 2) void gemm2_pipe(
    const __hip_bfloat16* __restrict__ Aall,   // h_bf [12][2048][512]
    const __hip_bfloat16* __restrict__ Ball,   // W2T  [12][2048][512]
    const float* __restrict__ bias,            // b2   [12][2048]
    const float* __restrict__ cs,
    float* __restrict__ O,
    f32x4* __restrict__ zeroBase, int doZero) {
  __shared__ __hip_bfloat16 lds[3 * 12288];    // 3 slots x (A 16KB + B 8KB) = 72 KiB
  const int orig = blockIdx.x + 16 * blockIdx.y + 128 * blockIdx.z;   // x fastest
  const int nw   = (orig & 7) * 192 + (orig >> 3);   // bijective, 1536 % 8 == 0
  const int bx   = nw & 15;
  const int by   = (nw >> 4) & 7;
  const int l    = nw >> 7;
  const int n0  = bx * 128;
  const int m0  = by * 256;
  const int tid = threadIdx.x;
  const int wid = tid >> 6, lane = tid & 63;
  const int wm  = wid >> 1, wn = wid & 1;
  const __hip_bfloat16* A  = Aall + (size_t)l * MROWS * HID;
  const __hip_bfloat16* Bt = Ball + (size_t)l * ODIM * HID;
  f32x4* zq = zeroBase + (size_t)nw * 4096;    // 64KB slice of [0, 96MB)
  const f32x4 zv = {0.f, 0.f, 0.f, 0.f};

  f32x4 acc[8][4];
#pragma unroll
  for (int m = 0; m < 8; ++m)
#pragma unroll
    for (int n = 0; n < 4; ++n)
      acc[m][n] = {0.f, 0.f, 0.f, 0.f};

  int ra[4], ca[4], rb[2], cb[2];
#pragma unroll
  for (int j = 0; j < 4; ++j) {
    int cx = j * 256 + tid;
    ra[j] = cx >> 2; ca[j] = (cx & 3) ^ ((ra[j] >> 1) & 3);
  }
#pragma unroll
  for (int j = 0; j < 2; ++j) {
    int cx = j * 256 + tid;
    rb[j] = cx >> 2; cb[j] = (cx & 3) ^ ((rb[j] >> 1) & 3);
  }

#define STAGE_A(slot, kt) do {                                                      \
    _Pragma("unroll")                                                               \
    for (int j_ = 0; j_ < 4; ++j_)                                                  \
      gload_lds16(A + (size_t)(m0 + ra[j_]) * HID + (kt) * 32 + ca[j_] * 8,         \
                  lds + (slot) * 12288 + j_ * 2048 + wid * 512);                    \
  } while (0)
#define STAGE_B(slot, kt) do {                                                      \
    _Pragma("unroll")                                                               \
    for (int j_ = 0; j_ < 2; ++j_)                                                  \
      gload_lds16(Bt + (size_t)(n0 + rb[j_]) * HID + (kt) * 32 + cb[j_] * 8,        \
                  lds + (slot) * 12288 + 8192 + j_ * 2048 + wid * 512);             \
  } while (0)

  const int kq   = lane >> 4;
  const int rl15 = lane & 15;

#define LD_FRAG(dst, base, rr) do {                                                 \
    int r_ = (rr);                                                                  \
    int off_ = r_ * 64 + ((kq ^ ((r_ >> 1) & 3)) << 4);                             \
    dst = *(const short8*)((const char*)(base) + off_);                             \
  } while (0)

  // prologue: 2 tiles in flight (6 loads/thread per tile)
  STAGE_A(0, 0); STAGE_B(0, 0);
  STAGE_A(1, 1); STAGE_B(1, 1);
  asm volatile("s_waitcnt vmcnt(6)" ::: "memory");   // tile 0 landed
  __builtin_amdgcn_s_barrier();

  const int NT = HID / 32;   // 16
  for (int t = 0; t < NT; ++t) {
    const int cur = t % 3;
    const __hip_bfloat16* sa = lds + cur * 12288;
    const __hip_bfloat16* sb = sa + 8192;
    short8 af[4], bfr[4];

    if (doZero)
      __builtin_nontemporal_store(zv, zq + t * 256 + tid);

    // ---- phase 0: m-frags 0..3 ----
#pragma unroll
    for (int n = 0; n < 4; ++n) LD_FRAG(bfr[n], sb, wn * 64 + n * 16 + rl15);
#pragma unroll
    for (int mi = 0; mi < 4; ++mi) LD_FRAG(af[mi], sa, wm * 128 + mi * 16 + rl15);
    if (t + 2 < NT) STAGE_A((t + 2) % 3, t + 2);
    __builtin_amdgcn_s_barrier();
    __builtin_amdgcn_s_setprio(1);
#pragma unroll
    for (int mi = 0; mi < 4; ++mi)
#pragma unroll
      for (int n = 0; n < 4; ++n)
        acc[mi][n] = __builtin_amdgcn_mfma_f32_16x16x32_bf16(af[mi], bfr[n], acc[mi][n], 0, 0, 0);
    __builtin_amdgcn_s_setprio(0);
    __builtin_amdgcn_s_barrier();

    // ---- phase 1: m-frags 4..7 (bfr reused) ----
#pragma unroll
    for (int mi = 0; mi < 4; ++mi) LD_FRAG(af[mi], sa, wm * 128 + 64 + mi * 16 + rl15);
    if (t + 2 < NT) STAGE_B((t + 2) % 3, t + 2);
    __builtin_amdgcn_s_barrier();
    __builtin_amdgcn_s_setprio(1);
#pragma unroll
    for (int mi = 0; mi < 4; ++mi)
#pragma unroll
      for (int n = 0; n < 4; ++n)
        acc[4 + mi][n] = __builtin_amdgcn_mfma_f32_16x16x32_bf16(af[mi], bfr[n], acc[4 + mi][n], 0, 0, 0);
    __builtin_amdgcn_s_setprio(0);
    if (t < NT - 2)       asm volatile("s_waitcnt vmcnt(6)" ::: "memory");
    else if (t == NT - 2) asm volatile("s_waitcnt vmcnt(0)" ::: "memory");
    __builtin_amdgcn_s_barrier();
  }
#undef STAGE_A
#undef STAGE_B
#undef LD_FRAG

  // ---- epilogue: bias + RoPE in-reg, per-wave LDS transpose, nt 1KB stores ----
  __syncthreads();
  const int head = bx;
  const int tkv  = wn;
  const int bidx = by * 2 + wm;
  float* slab = O + ((((size_t)(l + L_ACT) * 2 + tkv) * BDIM + bidx) * NHEAD + head) * (PDIM * DHEAD);
  const bool ropeWave = (tkv == 0);

  float bb[4];
#pragma unroll
  for (int n = 0; n < 4; ++n) bb[n] = bias[l * ODIM + n0 + wn * 64 + n * 16 + rl15];

  float* Tw = (float*)lds + wid * 2080;   // 32 x 65 f32 per wave

#pragma unroll
  for (int c = 0; c < 4; ++c) {           // p-chunk [c*32, c*32+32)
#pragma unroll
    for (int mh = 0; mh < 2; ++mh) {
      int mf = c * 2 + mh;
      int pl = mh * 16 + (lane >> 4) * 4;
#pragma unroll
      for (int n = 0; n < 4; ++n) {
#pragma unroll
        for (int j = 0; j < 4; ++j) {
          float v = acc[mf][n][j] + bb[n];
          if (ropeWave && n == 0) {
            float partner = __shfl_xor(v, 8);
            int p = c * 32 + pl + j;
            float cv = cs[p * 8 + (lane & 7)];
            float sv = cs[1024 + p * 8 + (lane & 7)];
            v = v * cv + (((lane & 15) < 8) ? -partner : partner) * sv;
          }
          Tw[(pl + j) * 65 + n * 16 + rl15] = v;
        }
      }
    }
#pragma unroll
    for (int it = 0; it < 8; ++it) {
      int pl = it * 4 + (lane >> 4);
      f32x4 vv = *(const f32x4*)(Tw + pl * 65 + rl15 * 4);
      __builtin_nontemporal_store(vv, (f32x4*)(slab + (size_t)(c * 32 + pl) * DHEAD + rl15 * 4));
    }
  }
}

extern "C" void kernel_launch(void* const* d_in, const int* in_sizes, int n_in,
                              void* d_out, int out_size, void* d_ws, size_t ws_size,
                              hipStream_t stream) {
  const float* summary   = (const float*)d_in[0];
  const int*   positions = (const int*)d_in[1];
  const float* W1 = (const float*)d_in[2];
  const float* b1 = (const float*)d_in[3];
  const float* W2 = (const float*)d_in[4];
  const float* b2 = (const float*)d_in[5];
  float* out = (float*)d_out;

  // Scratch: h_bf 25165824 | W2T 25165824 | cs 8192
  const size_t SCRATCH_BYTES = 25165824ULL + 25165824ULL + 8192ULL;
  const bool useWs = (ws_size >= SCRATCH_BYTES);
  char* sc = useWs ? (char*)d_ws : (char*)d_out;
  __hip_bfloat16* h_bf = (__hip_bfloat16*)sc;
  __hip_bfloat16* W2T  = (__hip_bfloat16*)(sc + 25165824);
  float*          cs   = (float*)(sc + 50331648);

  // zero region split: gemm2 covers [0, 100663296), gemm1 covers the rest.
  gemm1_128<<<dim3(HID / 128, MROWS / 128, L_ACT), 256, 0, stream>>>(
      summary, W1, positions, b1, h_bf, W2, W2T, cs,
      (f32x4*)((char*)d_out + 100663296), useWs ? 1 : 0);
  gemm2_pipe<<<dim3(ODIM / 128, MROWS / 256, L_ACT), 256, 0, stream>>>(
      h_bf, W2T, b2, cs, out, (f32x4*)d_out, useWs ? 1 : 0);

  if (!useWs)   // scratch aliased d_out: zero AFTER gemm2 has consumed it
    zerofill_kernel<<<2048, 256, 0, stream>>>((f32x4*)d_out, 12582912);
}

// Round 17
// 116.469 us; speedup vs baseline: 1.2572x; 1.0132x over previous
//
#include <hip/hip_runtime.h>
#include <hip/hip_bf16.h>

// Problem constants
#define L_ACT   12
#define BDIM    16
#define PDIM    128
#define DSUM    128
#define HID     512
#define ODIM    2048
#define NHEAD   16
#define DHEAD   64
#define MROWS   2048   // B*P rows per layer

typedef short s16x4  __attribute__((ext_vector_type(4)));
typedef short short8 __attribute__((ext_vector_type(8)));
typedef float f32x4  __attribute__((ext_vector_type(4)));

__device__ __forceinline__ void gload_lds16(const __hip_bfloat16* g, __hip_bfloat16* l) {
  __builtin_amdgcn_global_load_lds(
      (const __attribute__((address_space(1))) unsigned int*)g,
      (__attribute__((address_space(3))) unsigned int*)l, 16, 0, 0);
}

__device__ __forceinline__ short f2bf(float x) {
  __hip_bfloat16 h = __float2bfloat16(x);
  return *reinterpret_cast<short*>(&h);
}

// LDS-only barrier: gemm1's barriers order LDS state only; skipping the
// vmcnt(0) drain lets stores/prefetch loads pipeline across barriers.
#define LBAR() do {                                                   \
    asm volatile("s_waitcnt lgkmcnt(0)" ::: "memory");                \
    __builtin_amdgcn_s_barrier();                                     \
  } while (0)

// --- zero-fill (fallback path only) ---
__global__ __launch_bounds__(256) void zerofill_kernel(f32x4* __restrict__ p, int n16) {
  int stride = gridDim.x * 256;
  for (int i = blockIdx.x * 256 + threadIdx.x; i < n16; i += stride)
    p[i] = {0.f, 0.f, 0.f, 0.f};
}

// --- GEMM1: 128x128 tile, 4 waves, bias+relu, bf16 out.
//     A staged per-kt from f32 summary; B staged once per block from f32 W1
//     (persistent full-K swizzled tile). Block 0 computes cos/sin table.
//     H via LDS transpose; fused pipelined W2 -> W2T transpose with 64x64
//     tiles (256B read runs / 128B write runs, granule-XOR-swizzled LDS).
//     All barriers LDS-only; W2-tail loads pre-issued before the K-loop;
//     128KB nt zero-fill spread across all phases. ---
__global__ __launch_bounds__(256) void gemm1_128(
    const float* __restrict__ summary,          // [2048][128] f32
    const float* __restrict__ W1,               // [12][128][512] f32
    const int*   __restrict__ positions,
    const float* __restrict__ bias,
    __hip_bfloat16* __restrict__ Hall,
    const float* __restrict__ W2,
    __hip_bfloat16* __restrict__ W2T,
    float* __restrict__ cs,
    f32x4* __restrict__ zeroBase, int doZero) {
  const int KTOT = DSUM, NTOT = HID;
  __shared__ __hip_bfloat16 shbuf[24576];   // 49152B: B2 32KB | A 16KB (tail reuses)
  __hip_bfloat16* ldsB2 = shbuf;            // [128 r][256B] full-K swizzled B tile
  __hip_bfloat16* ldsA  = shbuf + 16384;    // per-kt A tile [128 r][128B]
  const int l    = blockIdx.z;
  const int n0   = blockIdx.x * 128;
  const int m0   = blockIdx.y * 128;
  const int tid  = threadIdx.x;
  const int wid  = tid >> 6;
  const int lane = tid & 63;
  const int wr = wid >> 1, wc = wid & 1;
  const int bid = blockIdx.x + 4 * blockIdx.y + 64 * blockIdx.z;   // 0..767

  const f32x4 z = {0.f, 0.f, 0.f, 0.f};
  f32x4* zp = zeroBase + (size_t)bid * 8192;   // 128KB chunk, slot groups 0..31

  // block 0: cos/sin table (consumed by gemm2; stream order guarantees visibility)
  if (bid == 0) {
#pragma unroll
    for (int q = 0; q < 4; ++q) {
      int i = q * 256 + tid;
      int p = i >> 3, f = i & 7;
      double inv = pow(10000.0, -(double)f / 8.0);
      double ang = (double)positions[p] * inv;
      cs[i]        = (float)cos(ang);
      cs[1024 + i] = (float)sin(ang);
    }
  }

  // W2-tail geometry: 4 tiles/block of 64j x 64o; reads 256B runs, writes 128B runs
  const int rowg = tid >> 4;          // 0..15 (j rows, +16p)
  const int colg = tid & 15;          // o granule (4 f32)
  const int orow = tid >> 3;          // 0..31 (o rows for store, +32p)
  const int jg   = tid & 7;           // j granule (8 bf16) for store
  const int tbase4 = bid * 4;
  f32x4 rvA0, rvA1, rvA2, rvA3, rvB0, rvB1, rvB2, rvB3;

#define W2_LOAD(P, tt_) do {                                                \
      int t_ = tbase4 + (tt_);                                              \
      int lz_ = t_ >> 8, rem_ = t_ & 255;                                   \
      int j0_ = (rem_ >> 5) * 64, o0_ = (rem_ & 31) * 64;                   \
      const float* ip_ = W2 + (size_t)lz_ * HID * ODIM                      \
                       + (size_t)(j0_ + rowg) * ODIM + o0_ + colg * 4;      \
      P##0 = *(const f32x4*)(ip_);                                          \
      P##1 = *(const f32x4*)(ip_ + (size_t)16 * ODIM);                      \
      P##2 = *(const f32x4*)(ip_ + (size_t)32 * ODIM);                      \
      P##3 = *(const f32x4*)(ip_ + (size_t)48 * ODIM);                      \
    } while (0)

  // B2 staging: W1[l][j][n0+r] -> ldsB2[r][(j4>>1)^(r&7)][j4&1]
  {
    const float* Wp = W1 + (size_t)l * DSUM * HID + n0;
#pragma unroll
    for (int q = 0; q < 16; ++q) {
      int g  = q * 256 + tid;
      int j4 = g >> 7;            // 0..31 (4 consecutive j)
      int r  = g & 127;
      s16x4 w;
#pragma unroll
      for (int jj = 0; jj < 4; ++jj)
        w[jj] = f2bf(Wp[(size_t)(j4 * 4 + jj) * HID + r]);
      int chunk = (j4 >> 1) ^ (r & 7);
      *(s16x4*)((char*)ldsB2 + r * 256 + chunk * 16 + (j4 & 1) * 8) = w;
    }
  }

  // pre-issue W2-tail tiles 0,1: HBM latency hides under K-loop + H epilogue
  W2_LOAD(rvA, 0);
  W2_LOAD(rvB, 1);

  f32x4 acc[4][4];
#pragma unroll
  for (int m = 0; m < 4; ++m)
#pragma unroll
    for (int n = 0; n < 4; ++n)
      acc[m][n] = {0.f, 0.f, 0.f, 0.f};

  const int kq = lane >> 4;

  for (int kt = 0; kt < KTOT / 64; ++kt) {
    LBAR();   // kt=0: orders B2 writes before reads; also guards ldsA reuse
    // zero slice during staging phase (slot groups 0..7)
    if (doZero) {
#pragma unroll
      for (int q = 0; q < 4; ++q)
        __builtin_nontemporal_store(z, zp + (kt * 4 + q) * 256 + tid);
    }
    // A: reg-staged f32 -> bf16, swizzled ds_write_b64
#pragma unroll
    for (int j = 0; j < 8; ++j) {
      int s = j * 256 + tid;
      int r = s >> 4, g = s & 15;
      f32x4 v = *(const f32x4*)(summary + (size_t)(m0 + r) * DSUM + kt * 64 + g * 4);
      s16x4 w;
      w[0] = f2bf(v[0]); w[1] = f2bf(v[1]); w[2] = f2bf(v[2]); w[3] = f2bf(v[3]);
      int ch = g >> 1;
      *(s16x4*)((char*)ldsA + r * 128 + ((ch ^ (r & 7)) << 4) + (g & 1) * 8) = w;
    }
    LBAR();
#pragma unroll
    for (int kk = 0; kk < 2; ++kk) {
      short8 af[4], bfr[4];
#pragma unroll
      for (int m = 0; m < 4; ++m) {
        int row = wr * 64 + m * 16 + (lane & 15);
        int off = (kk * 64 + kq * 16) ^ ((row & 7) << 4);
        af[m] = *(const short8*)((const char*)ldsA + row * 128 + off);
      }
#pragma unroll
      for (int n = 0; n < 4; ++n) {
        int row = wc * 64 + n * 16 + (lane & 15);
        int chunk = (kt * 8 + kk * 4 + kq) ^ (row & 7);
        bfr[n] = *(const short8*)((const char*)ldsB2 + row * 256 + chunk * 16);
      }
#pragma unroll
      for (int m = 0; m < 4; ++m)
#pragma unroll
        for (int n = 0; n < 4; ++n)
          acc[m][n] = __builtin_amdgcn_mfma_f32_16x16x32_bf16(af[m], bfr[n], acc[m][n], 0, 0, 0);
    }
  }

  // H epilogue via LDS: [128][136] bf16 padded tile -> 256B-run stores
  LBAR();   // all waves done reading B2/A staging
#pragma unroll
  for (int n = 0; n < 4; ++n) {
    int col = wc * 64 + n * 16 + (lane & 15);
    float bb = bias[l * NTOT + n0 + col];
#pragma unroll
    for (int m = 0; m < 4; ++m) {
      int rowb = wr * 64 + m * 16 + ((lane >> 4) << 2);
#pragma unroll
      for (int j = 0; j < 4; ++j) {
        float v = acc[m][n][j] + bb;
        v = v > 0.f ? v : 0.f;
        shbuf[(rowb + j) * 136 + col] = __float2bfloat16(v);
      }
    }
  }
  // zero slice during H scatter (slot groups 8..15)
  if (doZero) {
#pragma unroll
    for (int i = 0; i < 8; ++i)
      __builtin_nontemporal_store(z, zp + (8 + i) * 256 + tid);
  }
  LBAR();
  {
    __hip_bfloat16* H = Hall + (size_t)l * MROWS * HID;
#pragma unroll
    for (int i = 0; i < 8; ++i) {
      int idx = i * 256 + tid;
      int row = idx >> 4, seg = idx & 15;
      short8 v = *(const short8*)(shbuf + row * 136 + seg * 8);
      *(short8*)(H + (size_t)(m0 + row) * HID + n0 + seg * 8) = v;
    }
  }
  LBAR();   // H LDS reads done before W2 section overwrites shbuf

  // fused W2 -> W2T transpose: 4 x (64j x 64o) tiles, dbuf [64][68] f32 with
  // granule-XOR swizzle (col4' = col4 ^ (j>>3)), 2-deep reg prefetch,
  // 1 LDS-only barrier/tile, interleaved nt zero-fill (slot groups 16..31).
  {
    float* tb0 = (float*)shbuf;            // 64x68 f32 = 17408B
    float* tb1 = (float*)shbuf + 4352;

#define W2_WRITE(buf, P) do {                                               \
      _Pragma("unroll")                                                     \
      for (int p_ = 0; p_ < 4; ++p_) {                                      \
        int j_ = rowg + 16 * p_;                                            \
        f32x4 vv_ = (p_ == 0) ? P##0 : (p_ == 1) ? P##1 : (p_ == 2) ? P##2 : P##3; \
        *(f32x4*)&(buf)[j_ * 68 + 4 * (colg ^ (j_ >> 3))] = vv_;            \
      }                                                                     \
    } while (0)

#define W2_STORE(buf, tt_) do {                                             \
      int t_ = tbase4 + (tt_);                                              \
      int lz_ = t_ >> 8, rem_ = t_ & 255;                                   \
      int j0_ = (rem_ >> 5) * 64, o0_ = (rem_ & 31) * 64;                   \
      __hip_bfloat16* op_ = W2T + (size_t)lz_ * HID * ODIM;                 \
      _Pragma("unroll")                                                     \
      for (int p_ = 0; p_ < 2; ++p_) {                                      \
        int or_ = orow + 32 * p_;                                           \
        short8 w_;                                                          \
        _Pragma("unroll")                                                   \
        for (int i_ = 0; i_ < 8; ++i_)                                      \
          w_[i_] = f2bf((buf)[(jg * 8 + i_) * 68 + (or_ ^ (4 * jg))]);      \
        *(short8*)(op_ + (size_t)(o0_ + or_) * HID + j0_ + jg * 8) = w_;    \
      }                                                                     \
    } while (0)

#define ZCHUNK(tt_) do { if (doZero) {                                      \
      _Pragma("unroll")                                                     \
      for (int q_ = 0; q_ < 4; ++q_)                                        \
        __builtin_nontemporal_store(z, zp + (16 + (tt_) * 4 + q_) * 256 + tid); \
    } } while (0)

    W2_WRITE(tb0, rvA);
    LBAR();
#pragma unroll 1
    for (int tt = 0; tt < 4; tt += 2) {
      if (tt + 2 < 4) W2_LOAD(rvA, tt + 2);
      W2_STORE(tb0, tt);
      W2_WRITE(tb1, rvB);
      ZCHUNK(tt);
      LBAR();
      if (tt + 3 < 4) W2_LOAD(rvB, tt + 3);
      W2_STORE(tb1, tt + 1);
      if (tt + 2 < 4) W2_WRITE(tb0, rvA);
      ZCHUNK(tt + 1);
      LBAR();
    }
#undef W2_LOAD
#undef W2_WRITE
#undef W2_STORE
#undef ZCHUNK
  }
}

// --- GEMM2 (R12-proven, untouched): 256m x 128n tile, 256 threads (4 waves,
//     2Mx2N), BK=32, 3-slot LDS ring (72KB -> 2 blocks/CU), depth-2 prefetch
//     with counted vmcnt, 16x16x32 MFMA, XCD-chunked swizzle (1536 blocks),
//     per-t nt zero slice, LDS-transpose epilogue, nt 1KB slab stores. ---
__global__ __launch_bounds__(256, 2) void gemm2_pipe(
    const __hip_bfloat16* __restrict__ Aall,   // h_bf [12][2048][512]
    const __hip_bfloat16* __restrict__ Ball,   // W2T  [12][2048][512]
    const float* __restrict__ bias,            // b2   [12][2048]
    const float* __restrict__ cs,
    float* __restrict__ O,
    f32x4* __restrict__ zeroBase, int doZero) {
  __shared__ __hip_bfloat16 lds[3 * 12288];    // 3 slots x (A 16KB + B 8KB) = 72 KiB
  const int orig = blockIdx.x + 16 * blockIdx.y + 128 * blockIdx.z;   // x fastest
  const int nw   = (orig & 7) * 192 + (orig >> 3);   // bijective, 1536 % 8 == 0
  const int bx   = nw & 15;
  const int by   = (nw >> 4) & 7;
  const int l    = nw >> 7;
  const int n0  = bx * 128;
  const int m0  = by * 256;
  const int tid = threadIdx.x;
  const int wid = tid >> 6, lane = tid & 63;
  const int wm  = wid >> 1, wn = wid & 1;
  const __hip_bfloat16* A  = Aall + (size_t)l * MROWS * HID;
  const __hip_bfloat16* Bt = Ball + (size_t)l * ODIM * HID;
  f32x4* zq = zeroBase + (size_t)nw * 4096;    // 64KB slice of [0, 96MB)
  const f32x4 zv = {0.f, 0.f, 0.f, 0.f};

  f32x4 acc[8][4];
#pragma unroll
  for (int m = 0; m < 8; ++m)
#pragma unroll
    for (int n = 0; n < 4; ++n)
      acc[m][n] = {0.f, 0.f, 0.f, 0.f};

  int ra[4], ca[4], rb[2], cb[2];
#pragma unroll
  for (int j = 0; j < 4; ++j) {
    int cx = j * 256 + tid;
    ra[j] = cx >> 2; ca[j] = (cx & 3) ^ ((ra[j] >> 1) & 3);
  }
#pragma unroll
  for (int j = 0; j < 2; ++j) {
    int cx = j * 256 + tid;
    rb[j] = cx >> 2; cb[j] = (cx & 3) ^ ((rb[j] >> 1) & 3);
  }

#define STAGE_A(slot, kt) do {                                                      \
    _Pragma("unroll")                                                               \
    for (int j_ = 0; j_ < 4; ++j_)                                                  \
      gload_lds16(A + (size_t)(m0 + ra[j_]) * HID + (kt) * 32 + ca[j_] * 8,         \
                  lds + (slot) * 12288 + j_ * 2048 + wid * 512);                    \
  } while (0)
#define STAGE_B(slot, kt) do {                                                      \
    _Pragma("unroll")                                                               \
    for (int j_ = 0; j_ < 2; ++j_)                                                  \
      gload_lds16(Bt + (size_t)(n0 + rb[j_]) * HID + (kt) * 32 + cb[j_] * 8,        \
                  lds + (slot) * 12288 + 8192 + j_ * 2048 + wid * 512);             \
  } while (0)

  const int kq   = lane >> 4;
  const int rl15 = lane & 15;

#define LD_FRAG(dst, base, rr) do {                                                 \
    int r_ = (rr);                                                                  \
    int off_ = r_ * 64 + ((kq ^ ((r_ >> 1) & 3)) << 4);                             \
    dst = *(const short8*)((const char*)(base) + off_);                             \
  } while (0)

  // prologue: 2 tiles in flight (6 loads/thread per tile)
  STAGE_A(0, 0); STAGE_B(0, 0);
  STAGE_A(1, 1); STAGE_B(1, 1);
  asm volatile("s_waitcnt vmcnt(6)" ::: "memory");   // tile 0 landed
  __builtin_amdgcn_s_barrier();

  const int NT = HID / 32;   // 16
  for (int t = 0; t < NT; ++t) {
    const int cur = t % 3;
    const __hip_bfloat16* sa = lds + cur * 12288;
    const __hip_bfloat16* sb = sa + 8192;
    short8 af[4], bfr[4];

    if (doZero)
      __builtin_nontemporal_store(zv, zq + t * 256 + tid);

    // ---- phase 0: m-frags 0..3 ----
#pragma unroll
    for (int n = 0; n < 4; ++n) LD_FRAG(bfr[n], sb, wn * 64 + n * 16 + rl15);
#pragma unroll
    for (int mi = 0; mi < 4; ++mi) LD_FRAG(af[mi], sa, wm * 128 + mi * 16 + rl15);
    if (t + 2 < NT) STAGE_A((t + 2) % 3, t + 2);
    __builtin_amdgcn_s_barrier();
    __builtin_amdgcn_s_setprio(1);
#pragma unroll
    for (int mi = 0; mi < 4; ++mi)
#pragma unroll
      for (int n = 0; n < 4; ++n)
        acc[mi][n] = __builtin_amdgcn_mfma_f32_16x16x32_bf16(af[mi], bfr[n], acc[mi][n], 0, 0, 0);
    __builtin_amdgcn_s_setprio(0);
    __builtin_amdgcn_s_barrier();

    // ---- phase 1: m-frags 4..7 (bfr reused) ----
#pragma unroll
    for (int mi = 0; mi < 4; ++mi) LD_FRAG(af[mi], sa, wm * 128 + 64 + mi * 16 + rl15);
    if (t + 2 < NT) STAGE_B((t + 2) % 3, t + 2);
    __builtin_amdgcn_s_barrier();
    __builtin_amdgcn_s_setprio(1);
#pragma unroll
    for (int mi = 0; mi < 4; ++mi)
#pragma unroll
      for (int n = 0; n < 4; ++n)
        acc[4 + mi][n] = __builtin_amdgcn_mfma_f32_16x16x32_bf16(af[mi], bfr[n], acc[4 + mi][n], 0, 0, 0);
    __builtin_amdgcn_s_setprio(0);
    if (t < NT - 2)       asm volatile("s_waitcnt vmcnt(6)" ::: "memory");
    else if (t == NT - 2) asm volatile("s_waitcnt vmcnt(0)" ::: "memory");
    __builtin_amdgcn_s_barrier();
  }
#undef STAGE_A
#undef STAGE_B
#undef LD_FRAG

  // ---- epilogue: bias + RoPE in-reg, per-wave LDS transpose, nt 1KB stores ----
  __syncthreads();
  const int head = bx;
  const int tkv  = wn;
  const int bidx = by * 2 + wm;
  float* slab = O + ((((size_t)(l + L_ACT) * 2 + tkv) * BDIM + bidx) * NHEAD + head) * (PDIM * DHEAD);
  const bool ropeWave = (tkv == 0);

  float bb[4];
#pragma unroll
  for (int n = 0; n < 4; ++n) bb[n] = bias[l * ODIM + n0 + wn * 64 + n * 16 + rl15];

  float* Tw = (float*)lds + wid * 2080;   // 32 x 65 f32 per wave

#pragma unroll
  for (int c = 0; c < 4; ++c) {           // p-chunk [c*32, c*32+32)
#pragma unroll
    for (int mh = 0; mh < 2; ++mh) {
      int mf = c * 2 + mh;
      int pl = mh * 16 + (lane >> 4) * 4;
#pragma unroll
      for (int n = 0; n < 4; ++n) {
#pragma unroll
        for (int j = 0; j < 4; ++j) {
          float v = acc[mf][n][j] + bb[n];
          if (ropeWave && n == 0) {
            float partner = __shfl_xor(v, 8);
            int p = c * 32 + pl + j;
            float cv = cs[p * 8 + (lane & 7)];
            float sv = cs[1024 + p * 8 + (lane & 7)];
            v = v * cv + (((lane & 15) < 8) ? -partner : partner) * sv;
          }
          Tw[(pl + j) * 65 + n * 16 + rl15] = v;
        }
      }
    }
#pragma unroll
    for (int it = 0; it < 8; ++it) {
      int pl = it * 4 + (lane >> 4);
      f32x4 vv = *(const f32x4*)(Tw + pl * 65 + rl15 * 4);
      __builtin_nontemporal_store(vv, (f32x4*)(slab + (size_t)(c * 32 + pl) * DHEAD + rl15 * 4));
    }
  }
}

extern "C" void kernel_launch(void* const* d_in, const int* in_sizes, int n_in,
                              void* d_out, int out_size, void* d_ws, size_t ws_size,
                              hipStream_t stream) {
  const float* summary   = (const float*)d_in[0];
  const int*   positions = (const int*)d_in[1];
  const float* W1 = (const float*)d_in[2];
  const float* b1 = (const float*)d_in[3];
  const float* W2 = (const float*)d_in[4];
  const float* b2 = (const float*)d_in[5];
  float* out = (float*)d_out;

  // Scratch: h_bf 25165824 | W2T 25165824 | cs 8192
  const size_t SCRATCH_BYTES = 25165824ULL + 25165824ULL + 8192ULL;
  const bool useWs = (ws_size >= SCRATCH_BYTES);
  char* sc = useWs ? (char*)d_ws : (char*)d_out;
  __hip_bfloat16* h_bf = (__hip_bfloat16*)sc;
  __hip_bfloat16* W2T  = (__hip_bfloat16*)(sc + 25165824);
  float*          cs   = (float*)(sc + 50331648);

  // zero region split: gemm2 covers [0, 100663296), gemm1 covers the rest.
  gemm1_128<<<dim3(HID / 128, MROWS / 128, L_ACT), 256, 0, stream>>>(
      summary, W1, positions, b1, h_bf, W2, W2T, cs,
      (f32x4*)((char*)d_out + 100663296), useWs ? 1 : 0);
  gemm2_pipe<<<dim3(ODIM / 128, MROWS / 256, L_ACT), 256, 0, stream>>>(
      h_bf, W2T, b2, cs, out, (f32x4*)d_out, useWs ? 1 : 0);

  if (!useWs)   // scratch aliased d_out: zero AFTER gemm2 has consumed it
    zerofill_kernel<<<2048, 256, 0, stream>>>((f32x4*)d_out, 12582912);
}